// Round 5
// baseline (2855.202 us; speedup 1.0000x reference)
//
#include <hip/hip_runtime.h>
#include <hip/hip_bf16.h>

typedef __hip_bfloat16 bf16;

__device__ __forceinline__ float b2f(bf16 x) { return __bfloat162float(x); }

// ---------------- dtype probe (inputs proven fp32; probe kept as cheap insurance) ----------------
__global__ __launch_bounds__(64) void k_probe(const void* __restrict__ feat, int* __restrict__ mode) {
    const bf16* p = (const bf16*)feat;
    int lane = threadIdx.x;
    float m = 0.f;
    for (int i = lane; i < 2048; i += 64) {
        float v = fabsf(b2f(p[2 * i]));      // low half of fp32 i -> garbage if fp32
        if (!(v < 1e30f)) v = 1e30f;
        m = fmaxf(m, v);
    }
    #pragma unroll
    for (int off = 32; off > 0; off >>= 1) m = fmaxf(m, __shfl_xor(m, off, 64));
    if (lane == 0) *mode = (m > 1e8f) ? 1 : 0;   // 1 = inputs are fp32
}

__global__ __launch_bounds__(256) void k_stage(const void* __restrict__ in, float* __restrict__ out,
                                               int n, const int* __restrict__ mode) {
    int t = blockIdx.x * 256 + threadIdx.x;
    if (t >= n) return;
    if (*mode) out[t] = ((const float*)in)[t];
    else       out[t] = b2f(((const bf16*)in)[t]);
}

__global__ __launch_bounds__(256) void k_zero(float* __restrict__ p, int n) {
    int t = blockIdx.x * 256 + threadIdx.x;
    if (t < n) p[t] = 0.f;
}

// ---------------- dumb GEMM: one thread per output element ----------------
// X[N,128] @ [Wc | Wl] -> c < HC: Z[r*HC+c] ; c >= HC: Lin[r*HC+(c-HC)] = v + bc[c-HC]
template <int HC>
__global__ __launch_bounds__(256) void k_gemm_dumb(const float* __restrict__ X,
                                                   const float* __restrict__ Wc,
                                                   const float* __restrict__ Wl,
                                                   const float* __restrict__ bc,
                                                   float* __restrict__ Z, float* __restrict__ Lin,
                                                   int n) {
    int t = blockIdx.x * 256 + threadIdx.x;
    if (t >= n * 2 * HC) return;
    int r = t / (2 * HC);
    int c = t - r * (2 * HC);
    const float* xr = X + r * 128;
    float acc = 0.f;
    if (c < HC) {
        const float* wcol = Wc + c;
        #pragma unroll 8
        for (int k = 0; k < 128; k++) acc += xr[k] * wcol[k * HC];
        Z[r * HC + c] = acc;
    } else {
        int cc = c - HC;
        const float* wcol = Wl + cc;
        #pragma unroll 8
        for (int k = 0; k < 128; k++) acc += xr[k] * wcol[k * HC];
        Lin[r * HC + cc] = acc + bc[cc];
    }
}

// ---------------- el/er ----------------
template <int HC, int D>
__global__ __launch_bounds__(256) void k_elr(const float* __restrict__ Z, const float* __restrict__ al,
                                             const float* __restrict__ ar, float* __restrict__ el,
                                             float* __restrict__ er, int n) {
    int t = blockIdx.x * 256 + threadIdx.x;
    if (t >= n * 4) return;
    int node = t >> 2, h = t & 3;
    const float* zp = Z + node * HC + h * D;
    const float* alp = al + h * D;
    const float* arp = ar + h * D;
    float sl = 0.f, sr = 0.f;
    #pragma unroll
    for (int d = 0; d < D; d++) {
        float zv = zp[d];
        sl += zv * alp[d];
        sr += zv * arp[d];
    }
    el[t] = sl;
    er[t] = sr;
}

// ---------------- edge softmax via atomics (shift-invariant: no max-subtract needed, |e|<~8) ----------------
__global__ __launch_bounds__(256) void k_att1(const int* __restrict__ src, const int* __restrict__ dst,
                                              const float* __restrict__ el, const float* __restrict__ er,
                                              float* __restrict__ w, float* __restrict__ s, int e4) {
    int t = blockIdx.x * 256 + threadIdx.x;
    if (t >= e4) return;
    int e = t >> 2, h = t & 3;
    float x = el[src[e] * 4 + h] + er[dst[e] * 4 + h];
    x = x > 0.f ? x : 0.2f * x;
    float wv = __expf(x);
    w[t] = wv;
    atomicAdd(&s[dst[e] * 4 + h], wv);
}

__global__ __launch_bounds__(256) void k_att2(const int* __restrict__ dst, float* __restrict__ w,
                                              const float* __restrict__ s, int e4) {
    int t = blockIdx.x * 256 + threadIdx.x;
    if (t >= e4) return;
    int e = t >> 2, h = t & 3;
    w[t] = w[t] / s[dst[e] * 4 + h];
}

// per (edge, dim): Y[dst,d] += alpha[e,h(d)] * z[src,d]
template <int HC, int D>
__global__ __launch_bounds__(256) void k_agg(const int* __restrict__ src, const int* __restrict__ dst,
                                             const float* __restrict__ w, const float* __restrict__ z,
                                             float* __restrict__ Y, int total) {
    int t = blockIdx.x * 256 + threadIdx.x;
    if (t >= total) return;
    int e = t / HC;
    int d = t - e * HC;
    float val = w[e * 4 + d / D] * z[src[e] * HC + d];
    atomicAdd(&Y[dst[e] * HC + d], val);
}

// ---------------- BatchNorm ----------------

__global__ __launch_bounds__(128) void k_bn_stats(const float* __restrict__ Y, float* __restrict__ sum,
                                                  float* __restrict__ sumsq, int n) {
    int c = threadIdx.x;
    float s = 0.f, ss = 0.f;
    for (int r = blockIdx.x; r < n; r += gridDim.x) {
        float v = Y[r * 128 + c];
        s += v;
        ss += v * v;
    }
    atomicAdd(&sum[c], s);
    atomicAdd(&sumsq[c], ss);
}

__global__ __launch_bounds__(256) void k_bn_apply(const float* __restrict__ Y, const float* __restrict__ sum,
                                                  const float* __restrict__ sumsq, const float* __restrict__ g,
                                                  const float* __restrict__ b, float* __restrict__ out, int n) {
    int t = blockIdx.x * 256 + threadIdx.x;
    if (t >= n * 128) return;
    int c = t & 127;
    float invn = 1.f / (float)n;
    float mu = sum[c] * invn;
    float var = sumsq[c] * invn - mu * mu;
    float v = (Y[t] - mu) * rsqrtf(var + 1e-5f) * g[c] + b[c];
    out[t] = v > 0.f ? v : 0.f;
}

// ---------------- final: mean over heads + bias -> FP32 output ----------------

__global__ __launch_bounds__(256) void k_out(const float* __restrict__ Y, const float* __restrict__ bias,
                                             float* __restrict__ out, int n) {
    int t = blockIdx.x * 256 + threadIdx.x;
    if (t >= n * 40) return;
    int node = t / 40, c = t - node * 40;
    const float* y = Y + (size_t)node * 160;
    float v = 0.25f * (y[c] + y[40 + c] + y[80 + c] + y[120 + c]) + bias[c];
    out[t] = v;
}

// ---------------- launch ----------------

extern "C" void kernel_launch(void* const* d_in, const int* in_sizes, int n_in,
                              void* d_out, int out_size, void* d_ws, size_t ws_size,
                              hipStream_t stream) {
    (void)n_in; (void)out_size; (void)ws_size;
    const int N = in_sizes[0] / 128;     // feat is [N,128]
    const int E = in_sizes[1];           // src is [E]

    const int* src = (const int*)d_in[1];
    const int* dst = (const int*)d_in[2];
    float* out = (float*)d_out;          // reference output dtype is float32

    char* p = (char*)d_ws;
    auto carve = [&](size_t bytes) {
        void* q = (void*)p;
        p += (bytes + 255) & ~(size_t)255;
        return q;
    };
    int*   mode  = (int*)  carve(256);
    float* h_cur = (float*)carve((size_t)N * 128 * 4);
    float* zbuf  = (float*)carve((size_t)N * 160 * 4);
    float* lin   = (float*)carve((size_t)N * 160 * 4);
    float* el    = (float*)carve((size_t)N * 4 * 4);
    float* er    = (float*)carve((size_t)N * 4 * 4);
    float* wbuf  = (float*)carve((size_t)E * 4 * 4);
    float* sbuf  = (float*)carve((size_t)N * 4 * 4);
    float* bnbuf = (float*)carve(256 * 4);
    float* W32[23];
    for (int i = 3; i < 23; i++) W32[i] = (float*)carve((size_t)in_sizes[i] * 4);

    // dtype probe + staging to fp32
    k_probe<<<1, 64, 0, stream>>>(d_in[0], mode);
    k_stage<<<(N * 128 + 255) / 256, 256, 0, stream>>>(d_in[0], h_cur, N * 128, mode);
    for (int i = 3; i < 23; i++) {
        int n = in_sizes[i];
        k_stage<<<(n + 255) / 256, 256, 0, stream>>>(d_in[i], W32[i], n, mode);
    }

    const float* Wc[3] = {W32[3],  W32[8],  W32[13]};
    const float* al[3] = {W32[4],  W32[9],  W32[14]};
    const float* ar[3] = {W32[5],  W32[10], W32[15]};
    const float* bc[3] = {W32[6],  W32[11], W32[16]};
    const float* Wl[3] = {W32[7],  W32[12], W32[17]};
    const float* g0 = W32[18];
    const float* b0 = W32[19];
    const float* g1 = W32[20];
    const float* b1 = W32[21];
    const float* bias_last = W32[22];

    const int E4 = E * 4;
    const int EB4 = (E4 + 255) / 256;

    // ---- layers 0 and 1 (HC=128, D=32) ----
    for (int l = 0; l < 2; l++) {
        int gsz = N * 2 * 128;
        k_gemm_dumb<128><<<(gsz + 255) / 256, 256, 0, stream>>>(h_cur, Wc[l], Wl[l], bc[l], zbuf, lin, N);
        k_elr<128, 32><<<(N * 4 + 255) / 256, 256, 0, stream>>>(zbuf, al[l], ar[l], el, er, N);
        k_zero<<<(N * 4 + 255) / 256, 256, 0, stream>>>(sbuf, N * 4);
        k_att1<<<EB4, 256, 0, stream>>>(src, dst, el, er, wbuf, sbuf, E4);
        k_att2<<<EB4, 256, 0, stream>>>(dst, wbuf, sbuf, E4);
        int total = E * 128;
        k_agg<128, 32><<<(total + 255) / 256, 256, 0, stream>>>(src, dst, wbuf, zbuf, lin, total);
        k_zero<<<1, 256, 0, stream>>>(bnbuf, 256);
        k_bn_stats<<<256, 128, 0, stream>>>(lin, bnbuf, bnbuf + 128, N);
        const float* gg = (l == 0) ? g0 : g1;
        const float* bb = (l == 0) ? b0 : b1;
        k_bn_apply<<<(N * 128 + 255) / 256, 256, 0, stream>>>(lin, bnbuf, bnbuf + 128, gg, bb, h_cur, N);
    }

    // ---- layer 2 (HC=160, D=40) ----
    {
        int gsz = N * 2 * 160;
        k_gemm_dumb<160><<<(gsz + 255) / 256, 256, 0, stream>>>(h_cur, Wc[2], Wl[2], bc[2], zbuf, lin, N);
        k_elr<160, 40><<<(N * 4 + 255) / 256, 256, 0, stream>>>(zbuf, al[2], ar[2], el, er, N);
        k_zero<<<(N * 4 + 255) / 256, 256, 0, stream>>>(sbuf, N * 4);
        k_att1<<<EB4, 256, 0, stream>>>(src, dst, el, er, wbuf, sbuf, E4);
        k_att2<<<EB4, 256, 0, stream>>>(dst, wbuf, sbuf, E4);
        int total = E * 160;
        k_agg<160, 40><<<(total + 255) / 256, 256, 0, stream>>>(src, dst, wbuf, zbuf, lin, total);
        k_out<<<(N * 40 + 255) / 256, 256, 0, stream>>>(lin, bias_last, out, N);
    }
}

// Round 6
// 1157.998 us; speedup vs baseline: 2.4656x; 2.4656x over previous
//
#include <hip/hip_runtime.h>
#include <hip/hip_bf16.h>

typedef __hip_bfloat16 bf16;

__device__ __forceinline__ float b2f(bf16 x) { return __bfloat162float(x); }

// ---------------- dtype probe (inputs proven fp32; probe kept as cheap insurance) ----------------
__global__ __launch_bounds__(64) void k_probe(const void* __restrict__ feat, int* __restrict__ mode) {
    const bf16* p = (const bf16*)feat;
    int lane = threadIdx.x;
    float m = 0.f;
    for (int i = lane; i < 2048; i += 64) {
        float v = fabsf(b2f(p[2 * i]));
        if (!(v < 1e30f)) v = 1e30f;
        m = fmaxf(m, v);
    }
    #pragma unroll
    for (int off = 32; off > 0; off >>= 1) m = fmaxf(m, __shfl_xor(m, off, 64));
    if (lane == 0) *mode = (m > 1e8f) ? 1 : 0;   // 1 = inputs are fp32
}

__global__ __launch_bounds__(256) void k_stage(const void* __restrict__ in, float* __restrict__ out,
                                               int n, const int* __restrict__ mode) {
    int t = blockIdx.x * 256 + threadIdx.x;
    if (t >= n) return;
    if (*mode) out[t] = ((const float*)in)[t];
    else       out[t] = b2f(((const bf16*)in)[t]);
}

__global__ __launch_bounds__(256) void k_zero(float* __restrict__ p, int n) {
    int t = blockIdx.x * 256 + threadIdx.x;
    if (t < n) p[t] = 0.f;
}

// ---------------- CSR build (by dst) ----------------

__global__ __launch_bounds__(256) void k_hist(const int* __restrict__ dst, int* __restrict__ counts, int e) {
    int t = blockIdx.x * 256 + threadIdx.x;
    if (t < e) atomicAdd(&counts[dst[t]], 1);
}

__global__ __launch_bounds__(1024) void k_scan(const int* __restrict__ counts, int* __restrict__ row_ptr,
                                               int* __restrict__ cursor, int n) {
    __shared__ int wsum[16];
    __shared__ int carry_s;
    int lane = threadIdx.x & 63, w = threadIdx.x >> 6;
    if (threadIdx.x == 0) carry_s = 0;
    __syncthreads();
    for (int base = 0; base < n; base += 1024) {
        int i = base + (int)threadIdx.x;
        int v = (i < n) ? counts[i] : 0;
        int x = v;
        #pragma unroll
        for (int off = 1; off < 64; off <<= 1) {
            int t = __shfl_up(x, off, 64);
            if (lane >= off) x += t;
        }
        if (lane == 63) wsum[w] = x;
        __syncthreads();
        if (w == 0 && lane < 16) {
            int s = wsum[lane];
            #pragma unroll
            for (int off = 1; off < 16; off <<= 1) {
                int t = __shfl_up(s, off, 64);
                if (lane >= off) s += t;
            }
            wsum[lane] = s;
        }
        __syncthreads();
        int carry = carry_s;
        int woff = (w == 0) ? 0 : wsum[w - 1];
        int excl = carry + woff + x - v;
        if (i < n) { row_ptr[i] = excl; cursor[i] = excl; }
        __syncthreads();
        if (threadIdx.x == 0) carry_s = carry + wsum[15];
        __syncthreads();
    }
    if (threadIdx.x == 0) row_ptr[n] = carry_s;
}

// scatter {src, edge_id} pairs into CSR order
__global__ __launch_bounds__(256) void k_scatter(const int* __restrict__ src, const int* __restrict__ dst,
                                                 int* __restrict__ cursor, int2* __restrict__ spair, int e) {
    int t = blockIdx.x * 256 + threadIdx.x;
    if (t < e) {
        int d = dst[t];
        int idx = atomicAdd(&cursor[d], 1);
        spair[idx] = make_int2(src[t], t);
    }
}

// ---------------- tiled GEMM: X[N,128] @ [Wc|Wl][128,2*HC] -> Z fp32 | Lin fp32 (no bias) ----------------
template <int HC>
__global__ __launch_bounds__(256) void k_gemm(const float* __restrict__ A,
                                              const float* __restrict__ Wc, const float* __restrict__ Wl,
                                              float* __restrict__ Z, float* __restrict__ Lin, int n) {
    __shared__ float As[16][68];
    __shared__ float Bs[16][68];
    int tid = threadIdx.x;
    int tx = tid & 15, ty = tid >> 4;
    int row0 = blockIdx.x * 64, col0 = blockIdx.y * 64;
    float acc[4][4] = {{0.f}};
    for (int k0 = 0; k0 < 128; k0 += 16) {
        #pragma unroll
        for (int i = 0; i < 4; i++) {
            int e = tid + i * 256;          // [64 rows][16 k]
            int m = e >> 4, kk = e & 15;
            int r = row0 + m;
            As[kk][m] = (r < n) ? A[r * 128 + k0 + kk] : 0.f;
        }
        #pragma unroll
        for (int i = 0; i < 4; i++) {
            int e = tid + i * 256;          // [16 k][64 cols]
            int kk = e >> 6, c = e & 63;
            int gc = col0 + c;
            float wv;
            if (gc < HC) wv = Wc[(k0 + kk) * HC + gc];
            else         wv = Wl[(k0 + kk) * HC + gc - HC];
            Bs[kk][c] = wv;
        }
        __syncthreads();
        #pragma unroll
        for (int kk = 0; kk < 16; kk++) {
            float4 av = *(const float4*)&As[kk][ty * 4];
            float4 bv = *(const float4*)&Bs[kk][tx * 4];
            float a[4] = {av.x, av.y, av.z, av.w};
            float b[4] = {bv.x, bv.y, bv.z, bv.w};
            #pragma unroll
            for (int i = 0; i < 4; i++)
                #pragma unroll
                for (int j = 0; j < 4; j++)
                    acc[i][j] += a[i] * b[j];
        }
        __syncthreads();
    }
    #pragma unroll
    for (int i = 0; i < 4; i++) {
        int r = row0 + ty * 4 + i;
        if (r >= n) continue;
        #pragma unroll
        for (int j = 0; j < 4; j++) {
            int gc = col0 + tx * 4 + j;
            float v = acc[i][j];
            if (gc < HC) Z[(size_t)r * HC + gc] = v;
            else         Lin[(size_t)r * HC + gc - HC] = v;
        }
    }
}

// ---------------- el/er ----------------
template <int HC, int D>
__global__ __launch_bounds__(256) void k_elr(const float* __restrict__ Z, const float* __restrict__ al,
                                             const float* __restrict__ ar, float* __restrict__ el,
                                             float* __restrict__ er, int n) {
    int t = blockIdx.x * 256 + threadIdx.x;
    if (t >= n * 4) return;
    int node = t >> 2, h = t & 3;
    const float* zp = Z + (size_t)node * HC + h * D;
    const float* alp = al + h * D;
    const float* arp = ar + h * D;
    float sl = 0.f, sr = 0.f;
    #pragma unroll
    for (int d = 0; d < D; d++) {
        float zv = zp[d];
        sl += zv * alp[d];
        sr += zv * arp[d];
    }
    el[t] = sl;
    er[t] = sr;
}

// ---------------- per-edge unnormalized weights + per-node sums (shift-invariant softmax) ----------------
__global__ __launch_bounds__(256) void k_att1(const int* __restrict__ src, const int* __restrict__ dst,
                                              const float* __restrict__ el, const float* __restrict__ er,
                                              float* __restrict__ w, float* __restrict__ s, int e4) {
    int t = blockIdx.x * 256 + threadIdx.x;
    if (t >= e4) return;
    int e = t >> 2, h = t & 3;
    float x = el[src[e] * 4 + h] + er[dst[e] * 4 + h];
    x = x > 0.f ? x : 0.2f * x;
    float wv = __expf(x);
    w[t] = wv;
    atomicAdd(&s[dst[e] * 4 + h], wv);
}

// ---------------- wave-per-node gather: Y[dst] += (1/s) * sum_e w_e * Z[src_e] + bc ----------------
template <int HC, int D>
__global__ __launch_bounds__(256) void k_gather(const int* __restrict__ row_ptr, const int2* __restrict__ spair,
                                                const float* __restrict__ w, const float* __restrict__ s,
                                                const float* __restrict__ bc, const float* __restrict__ Z,
                                                float* __restrict__ Y, int n) {
    constexpr int VPL = (HC + 63) / 64;
    int wv = (int)((blockIdx.x * blockDim.x + threadIdx.x) >> 6);
    int lane = threadIdx.x & 63;
    if (wv >= n) return;
    int beg = row_ptr[wv], end = row_ptr[wv + 1];
    const float4* w4 = (const float4*)w;
    float acc[VPL];
    #pragma unroll
    for (int j = 0; j < VPL; j++) acc[j] = 0.f;
    for (int i = beg; i < end; i++) {
        int2 pe = spair[i];               // broadcast load (all lanes same addr)
        float4 wv4 = w4[pe.y];            // w[e*4 .. e*4+3]
        float wh[4] = {wv4.x, wv4.y, wv4.z, wv4.w};
        const float* zrow = Z + (size_t)pe.x * HC;
        #pragma unroll
        for (int j = 0; j < VPL; j++) {
            int d = lane + j * 64;
            if (d < HC) acc[j] += wh[d / D] * zrow[d];
        }
    }
    int deg = end - beg;
    float inv[4];
    #pragma unroll
    for (int h = 0; h < 4; h++) inv[h] = (deg > 0) ? 1.f / s[wv * 4 + h] : 0.f;
    #pragma unroll
    for (int j = 0; j < VPL; j++) {
        int d = lane + j * 64;
        if (d < HC) {
            size_t idx = (size_t)wv * HC + d;
            Y[idx] = acc[j] * inv[d / D] + bc[d] + Y[idx];
        }
    }
}

// ---------------- BatchNorm ----------------

__global__ __launch_bounds__(128) void k_bn_stats(const float* __restrict__ Y, float* __restrict__ sum,
                                                  float* __restrict__ sumsq, int n) {
    int c = threadIdx.x;
    float s = 0.f, ss = 0.f;
    for (int r = blockIdx.x; r < n; r += gridDim.x) {
        float v = Y[r * 128 + c];
        s += v;
        ss += v * v;
    }
    atomicAdd(&sum[c], s);
    atomicAdd(&sumsq[c], ss);
}

__global__ __launch_bounds__(256) void k_bn_apply(const float* __restrict__ Y, const float* __restrict__ sum,
                                                  const float* __restrict__ sumsq, const float* __restrict__ g,
                                                  const float* __restrict__ b, float* __restrict__ out, int n) {
    int t = blockIdx.x * 256 + threadIdx.x;
    if (t >= n * 128) return;
    int c = t & 127;
    float invn = 1.f / (float)n;
    float mu = sum[c] * invn;
    float var = sumsq[c] * invn - mu * mu;
    float v = (Y[t] - mu) * rsqrtf(var + 1e-5f) * g[c] + b[c];
    out[t] = v > 0.f ? v : 0.f;
}

// ---------------- final: mean over heads + bias -> fp32 ----------------

__global__ __launch_bounds__(256) void k_out(const float* __restrict__ Y, const float* __restrict__ bias,
                                             float* __restrict__ out, int n) {
    int t = blockIdx.x * 256 + threadIdx.x;
    if (t >= n * 40) return;
    int node = t / 40, c = t - node * 40;
    const float* y = Y + (size_t)node * 160;
    out[t] = 0.25f * (y[c] + y[40 + c] + y[80 + c] + y[120 + c]) + bias[c];
}

// ---------------- launch ----------------

extern "C" void kernel_launch(void* const* d_in, const int* in_sizes, int n_in,
                              void* d_out, int out_size, void* d_ws, size_t ws_size,
                              hipStream_t stream) {
    (void)n_in; (void)out_size; (void)ws_size;
    const int N = in_sizes[0] / 128;
    const int E = in_sizes[1];

    const int* src = (const int*)d_in[1];
    const int* dst = (const int*)d_in[2];
    float* out = (float*)d_out;

    char* p = (char*)d_ws;
    auto carve = [&](size_t bytes) {
        void* q = (void*)p;
        p += (bytes + 255) & ~(size_t)255;
        return q;
    };
    int*   mode    = (int*)  carve(256);
    float* h_cur   = (float*)carve((size_t)N * 128 * 4);
    float* zbuf    = (float*)carve((size_t)N * 160 * 4);
    float* lin     = (float*)carve((size_t)N * 160 * 4);
    float* el      = (float*)carve((size_t)N * 4 * 4);
    float* er      = (float*)carve((size_t)N * 4 * 4);
    float* wbuf    = (float*)carve((size_t)E * 4 * 4);
    float* sbuf    = (float*)carve((size_t)N * 4 * 4);
    float* bnbuf   = (float*)carve(256 * 4);
    int*   counts  = (int*)  carve((size_t)N * 4);
    int*   row_ptr = (int*)  carve((size_t)(N + 1) * 4);
    int*   cursor  = (int*)  carve((size_t)N * 4);
    int2*  spair   = (int2*) carve((size_t)E * 8);
    float* W32[23];
    for (int i = 3; i < 23; i++) W32[i] = (float*)carve((size_t)in_sizes[i] * 4);

    // staging to fp32
    k_probe<<<1, 64, 0, stream>>>(d_in[0], mode);
    k_stage<<<(N * 128 + 255) / 256, 256, 0, stream>>>(d_in[0], h_cur, N * 128, mode);
    for (int i = 3; i < 23; i++) {
        int n = in_sizes[i];
        k_stage<<<(n + 255) / 256, 256, 0, stream>>>(d_in[i], W32[i], n, mode);
    }

    const float* Wc[3] = {W32[3],  W32[8],  W32[13]};
    const float* al[3] = {W32[4],  W32[9],  W32[14]};
    const float* ar[3] = {W32[5],  W32[10], W32[15]};
    const float* bc[3] = {W32[6],  W32[11], W32[16]};
    const float* Wl[3] = {W32[7],  W32[12], W32[17]};
    const float* g0 = W32[18];
    const float* b0 = W32[19];
    const float* g1 = W32[20];
    const float* b1 = W32[21];
    const float* bias_last = W32[22];

    const int E4 = E * 4;
    const int EB4 = (E4 + 255) / 256;
    const int EB = (E + 255) / 256;
    const int GB_ROWS = (N + 63) / 64;
    const int NODE_BLK = (N + 3) / 4;      // 4 waves/block

    // CSR by dst (shared across layers)
    k_zero<<<(N + 255) / 256, 256, 0, stream>>>((float*)counts, N);
    k_hist<<<EB, 256, 0, stream>>>(dst, counts, E);
    k_scan<<<1, 1024, 0, stream>>>(counts, row_ptr, cursor, N);
    k_scatter<<<EB, 256, 0, stream>>>(src, dst, cursor, spair, E);

    // ---- layers 0 and 1 (HC=128, D=32) ----
    for (int l = 0; l < 2; l++) {
        k_gemm<128><<<dim3(GB_ROWS, 4), 256, 0, stream>>>(h_cur, Wc[l], Wl[l], zbuf, lin, N);
        k_elr<128, 32><<<(N * 4 + 255) / 256, 256, 0, stream>>>(zbuf, al[l], ar[l], el, er, N);
        k_zero<<<(N * 4 + 255) / 256, 256, 0, stream>>>(sbuf, N * 4);
        k_att1<<<EB4, 256, 0, stream>>>(src, dst, el, er, wbuf, sbuf, E4);
        k_gather<128, 32><<<NODE_BLK, 256, 0, stream>>>(row_ptr, spair, wbuf, sbuf, bc[l], zbuf, lin, N);
        k_zero<<<1, 256, 0, stream>>>(bnbuf, 256);
        k_bn_stats<<<256, 128, 0, stream>>>(lin, bnbuf, bnbuf + 128, N);
        const float* gg = (l == 0) ? g0 : g1;
        const float* bb = (l == 0) ? b0 : b1;
        k_bn_apply<<<(N * 128 + 255) / 256, 256, 0, stream>>>(lin, bnbuf, bnbuf + 128, gg, bb, h_cur, N);
    }

    // ---- layer 2 (HC=160, D=40) ----
    k_gemm<160><<<dim3(GB_ROWS, 5), 256, 0, stream>>>(h_cur, Wc[2], Wl[2], zbuf, lin, N);
    k_elr<160, 40><<<(N * 4 + 255) / 256, 256, 0, stream>>>(zbuf, al[2], ar[2], el, er, N);
    k_zero<<<(N * 4 + 255) / 256, 256, 0, stream>>>(sbuf, N * 4);
    k_att1<<<EB4, 256, 0, stream>>>(src, dst, el, er, wbuf, sbuf, E4);
    k_gather<160, 40><<<NODE_BLK, 256, 0, stream>>>(row_ptr, spair, wbuf, sbuf, bc[2], zbuf, lin, N);
    k_out<<<(N * 40 + 255) / 256, 256, 0, stream>>>(lin, bias_last, out, N);
}

// Round 7
// 1060.676 us; speedup vs baseline: 2.6919x; 1.0918x over previous
//
#include <hip/hip_runtime.h>
#include <hip/hip_bf16.h>

typedef __hip_bfloat16 bf16;
typedef __attribute__((ext_vector_type(8))) short short8;   // 8 bf16 = 4 VGPRs
typedef __attribute__((ext_vector_type(4))) float f32x4;

__device__ __forceinline__ float b2f(bf16 x) { return __bfloat162float(x); }

// ---------------- dtype probe (inputs proven fp32; kept as cheap insurance) ----------------
__global__ __launch_bounds__(64) void k_probe(const void* __restrict__ feat, int* __restrict__ mode) {
    const bf16* p = (const bf16*)feat;
    int lane = threadIdx.x;
    float m = 0.f;
    for (int i = lane; i < 2048; i += 64) {
        float v = fabsf(b2f(p[2 * i]));
        if (!(v < 1e30f)) v = 1e30f;
        m = fmaxf(m, v);
    }
    #pragma unroll
    for (int off = 32; off > 0; off >>= 1) m = fmaxf(m, __shfl_xor(m, off, 64));
    if (lane == 0) *mode = (m > 1e8f) ? 1 : 0;   // 1 = inputs are fp32
}

__global__ __launch_bounds__(256) void k_stage(const void* __restrict__ in, float* __restrict__ out,
                                               int n, const int* __restrict__ mode) {
    int t = blockIdx.x * 256 + threadIdx.x;
    if (t >= n) return;
    if (*mode) out[t] = ((const float*)in)[t];
    else       out[t] = b2f(((const bf16*)in)[t]);
}

// stage feat -> bf16 (GEMM A operand)
__global__ __launch_bounds__(256) void k_stage_bf(const void* __restrict__ in, bf16* __restrict__ out,
                                                  int n, const int* __restrict__ mode) {
    int t = blockIdx.x * 256 + threadIdx.x;
    if (t >= n) return;
    if (*mode) out[t] = __float2bfloat16(((const float*)in)[t]);
    else       out[t] = ((const bf16*)in)[t];
}

__global__ __launch_bounds__(256) void k_zero(float* __restrict__ p, int n) {
    int t = blockIdx.x * 256 + threadIdx.x;
    if (t < n) p[t] = 0.f;
}

// ---------------- CSR build (by dst) ----------------

__global__ __launch_bounds__(256) void k_hist(const int* __restrict__ dst, int* __restrict__ counts, int e) {
    int t = blockIdx.x * 256 + threadIdx.x;
    if (t < e) atomicAdd(&counts[dst[t]], 1);
}

__global__ __launch_bounds__(1024) void k_scan(const int* __restrict__ counts, int* __restrict__ row_ptr,
                                               int* __restrict__ cursor, int n) {
    __shared__ int wsum[16];
    __shared__ int carry_s;
    int lane = threadIdx.x & 63, w = threadIdx.x >> 6;
    if (threadIdx.x == 0) carry_s = 0;
    __syncthreads();
    for (int base = 0; base < n; base += 1024) {
        int i = base + (int)threadIdx.x;
        int v = (i < n) ? counts[i] : 0;
        int x = v;
        #pragma unroll
        for (int off = 1; off < 64; off <<= 1) {
            int t = __shfl_up(x, off, 64);
            if (lane >= off) x += t;
        }
        if (lane == 63) wsum[w] = x;
        __syncthreads();
        if (w == 0 && lane < 16) {
            int s = wsum[lane];
            #pragma unroll
            for (int off = 1; off < 16; off <<= 1) {
                int t = __shfl_up(s, off, 64);
                if (lane >= off) s += t;
            }
            wsum[lane] = s;
        }
        __syncthreads();
        int carry = carry_s;
        int woff = (w == 0) ? 0 : wsum[w - 1];
        int excl = carry + woff + x - v;
        if (i < n) { row_ptr[i] = excl; cursor[i] = excl; }
        __syncthreads();
        if (threadIdx.x == 0) carry_s = carry + wsum[15];
        __syncthreads();
    }
    if (threadIdx.x == 0) row_ptr[n] = carry_s;
}

__global__ __launch_bounds__(256) void k_scatter(const int* __restrict__ src, const int* __restrict__ dst,
                                                 int* __restrict__ cursor, int2* __restrict__ spair, int e) {
    int t = blockIdx.x * 256 + threadIdx.x;
    if (t < e) {
        int d = dst[t];
        int idx = atomicAdd(&cursor[d], 1);
        spair[idx] = make_int2(src[t], t);
    }
}

// ---------------- weight transpose+cast: Wt[c][k] = bf16([Wc|Wl][k][c]) ----------------
template <int HC>
__global__ __launch_bounds__(256) void k_wt(const float* __restrict__ Wc, const float* __restrict__ Wl,
                                            bf16* __restrict__ Wt) {
    int t = blockIdx.x * 256 + threadIdx.x;
    if (t >= 2 * HC * 128) return;
    int k = t & 127, c = t >> 7;
    float v = (c < HC) ? Wc[k * HC + c] : Wl[k * HC + c - HC];
    Wt[(size_t)c * 128 + k] = __float2bfloat16(v);
}

// ---------------- MFMA GEMM: A[N,128]bf16 @ Wt[2HC,128]bf16 -> Zf f32 | Zh bf16 | Lin f32 ----------------
// 64x64 block tile, 4 waves, wave w -> rows [w*16, w*16+16), 4 col-tiles of 16.
// Frag layouts (HW-verified, docs §3): A[m=lane&15][k=quad*8+j]; B[k=quad*8+j][n=lane&15];
// C/D: col=lane&15, row=quad*4+reg.
template <int HC>
__global__ __launch_bounds__(256) void k_gemm_mfma(const bf16* __restrict__ A, const bf16* __restrict__ Wt,
                                                   float* __restrict__ Zf, bf16* __restrict__ Zh,
                                                   float* __restrict__ Lin, int n) {
    int tid = threadIdx.x;
    int wv = tid >> 6, lane = tid & 63;
    int quad = lane >> 4, m16 = lane & 15;
    int row0 = blockIdx.x * 64 + wv * 16;
    int col0 = blockIdx.y * 64;
    f32x4 acc[4] = {};
    int ar = row0 + m16;
    if (ar >= n) ar = n - 1;
    const short8* Arow = (const short8*)(A + (size_t)ar * 128);   // 16 x short8 per row
    #pragma unroll
    for (int k8 = 0; k8 < 16; k8 += 4) {    // k0 = k8*8, steps of 32
        short8 a = Arow[k8 + quad];
        #pragma unroll
        for (int c = 0; c < 4; c++) {
            const short8* Brow = (const short8*)(Wt + (size_t)(col0 + c * 16 + m16) * 128);
            short8 b = Brow[k8 + quad];
            acc[c] = __builtin_amdgcn_mfma_f32_16x16x32_bf16(a, b, acc[c], 0, 0, 0);
        }
    }
    #pragma unroll
    for (int c = 0; c < 4; c++) {
        int gc = col0 + c * 16 + m16;
        #pragma unroll
        for (int reg = 0; reg < 4; reg++) {
            int r = row0 + quad * 4 + reg;
            if (r >= n) continue;
            float v = acc[c][reg];
            if (gc < HC) {
                Zf[(size_t)r * HC + gc] = v;
                Zh[(size_t)r * HC + gc] = __float2bfloat16(v);
            } else {
                Lin[(size_t)r * HC + gc - HC] = v;
            }
        }
    }
}

// ---------------- el/er from fp32 Z ----------------
template <int HC, int D>
__global__ __launch_bounds__(256) void k_elr(const float* __restrict__ Z, const float* __restrict__ al,
                                             const float* __restrict__ ar, float* __restrict__ el,
                                             float* __restrict__ er, int n) {
    int t = blockIdx.x * 256 + threadIdx.x;
    if (t >= n * 4) return;
    int node = t >> 2, h = t & 3;
    const float* zp = Z + (size_t)node * HC + h * D;
    const float* alp = al + h * D;
    const float* arp = ar + h * D;
    float sl = 0.f, sr = 0.f;
    #pragma unroll
    for (int d = 0; d < D; d++) {
        float zv = zp[d];
        sl += zv * alp[d];
        sr += zv * arp[d];
    }
    el[t] = sl;
    er[t] = sr;
}

// ---------------- per-edge weights + per-node sums (shift-invariant softmax, |e| small) ----------------
__global__ __launch_bounds__(256) void k_att1(const int* __restrict__ src, const int* __restrict__ dst,
                                              const float* __restrict__ el, const float* __restrict__ er,
                                              float* __restrict__ w, float* __restrict__ s, int e4) {
    int t = blockIdx.x * 256 + threadIdx.x;
    if (t >= e4) return;
    int e = t >> 2, h = t & 3;
    float x = el[src[e] * 4 + h] + er[dst[e] * 4 + h];
    x = x > 0.f ? x : 0.2f * x;
    float wv = __expf(x);
    w[t] = wv;
    atomicAdd(&s[dst[e] * 4 + h], wv);
}

// ---------------- wave-per-node gather from bf16 Z: Y += (1/s)*sum w_e*Z[src] + bc ----------------
template <int HC, int D>
__global__ __launch_bounds__(256) void k_gather(const int* __restrict__ row_ptr, const int2* __restrict__ spair,
                                                const float* __restrict__ w, const float* __restrict__ s,
                                                const float* __restrict__ bc, const bf16* __restrict__ Z,
                                                float* __restrict__ Y, int n) {
    constexpr int VP2 = HC / 2;            // bf16 pairs per row (64 or 80); D even => pair never straddles heads
    int wv = (int)((blockIdx.x * blockDim.x + threadIdx.x) >> 6);
    int lane = threadIdx.x & 63;
    if (wv >= n) return;
    int beg = row_ptr[wv], end = row_ptr[wv + 1];
    const float4* w4 = (const float4*)w;
    const int h0 = (2 * lane) / D;
    const int h1 = (VP2 > 64) ? (2 * (lane + 64)) / D : 0;
    const bool has1 = (VP2 > 64) && (lane < VP2 - 64);
    float2 a0 = {0.f, 0.f}, a1 = {0.f, 0.f};
    for (int i = beg; i < end; i++) {
        int2 pe = spair[i];                 // broadcast
        float4 wv4 = w4[pe.y];              // broadcast
        float warr[4] = {wv4.x, wv4.y, wv4.z, wv4.w};
        const __hip_bfloat162* zr = (const __hip_bfloat162*)(Z + (size_t)pe.x * HC);
        __hip_bfloat162 z0 = zr[lane];
        float w0 = warr[h0];
        a0.x += w0 * b2f(z0.x);
        a0.y += w0 * b2f(z0.y);
        if (has1) {
            __hip_bfloat162 z1 = zr[lane + 64];
            float w1 = warr[h1];
            a1.x += w1 * b2f(z1.x);
            a1.y += w1 * b2f(z1.y);
        }
    }
    int deg = end - beg;
    float inv[4];
    #pragma unroll
    for (int h = 0; h < 4; h++) inv[h] = (deg > 0) ? 1.f / s[wv * 4 + h] : 0.f;
    float2* Y2 = (float2*)(Y + (size_t)wv * HC);
    const float2* bc2 = (const float2*)bc;
    float2 y0 = Y2[lane], b0 = bc2[lane];
    y0.x += a0.x * inv[h0] + b0.x;
    y0.y += a0.y * inv[h0] + b0.y;
    Y2[lane] = y0;
    if (has1) {
        float2 y1 = Y2[lane + 64], b1 = bc2[lane + 64];
        y1.x += a1.x * inv[h1] + b1.x;
        y1.y += a1.y * inv[h1] + b1.y;
        Y2[lane + 64] = y1;
    }
}

// ---------------- BatchNorm ----------------

__global__ __launch_bounds__(128) void k_bn_stats(const float* __restrict__ Y, float* __restrict__ sum,
                                                  float* __restrict__ sumsq, int n) {
    int c = threadIdx.x;
    float s = 0.f, ss = 0.f;
    for (int r = blockIdx.x; r < n; r += gridDim.x) {
        float v = Y[r * 128 + c];
        s += v;
        ss += v * v;
    }
    atomicAdd(&sum[c], s);
    atomicAdd(&sumsq[c], ss);
}

// BN + ReLU -> bf16 (next layer's GEMM A operand)
__global__ __launch_bounds__(256) void k_bn_apply(const float* __restrict__ Y, const float* __restrict__ sum,
                                                  const float* __restrict__ sumsq, const float* __restrict__ g,
                                                  const float* __restrict__ b, bf16* __restrict__ out, int n) {
    int t = blockIdx.x * 256 + threadIdx.x;
    if (t >= n * 128) return;
    int c = t & 127;
    float invn = 1.f / (float)n;
    float mu = sum[c] * invn;
    float var = sumsq[c] * invn - mu * mu;
    float v = (Y[t] - mu) * rsqrtf(var + 1e-5f) * g[c] + b[c];
    out[t] = __float2bfloat16(v > 0.f ? v : 0.f);
}

// ---------------- final: mean over heads + bias -> fp32 ----------------

__global__ __launch_bounds__(256) void k_out(const float* __restrict__ Y, const float* __restrict__ bias,
                                             float* __restrict__ out, int n) {
    int t = blockIdx.x * 256 + threadIdx.x;
    if (t >= n * 40) return;
    int node = t / 40, c = t - node * 40;
    const float* y = Y + (size_t)node * 160;
    out[t] = 0.25f * (y[c] + y[40 + c] + y[80 + c] + y[120 + c]) + bias[c];
}

// ---------------- launch ----------------

extern "C" void kernel_launch(void* const* d_in, const int* in_sizes, int n_in,
                              void* d_out, int out_size, void* d_ws, size_t ws_size,
                              hipStream_t stream) {
    (void)n_in; (void)out_size; (void)ws_size;
    const int N = in_sizes[0] / 128;
    const int E = in_sizes[1];

    const int* src = (const int*)d_in[1];
    const int* dst = (const int*)d_in[2];
    float* out = (float*)d_out;

    char* p = (char*)d_ws;
    auto carve = [&](size_t bytes) {
        void* q = (void*)p;
        p += (bytes + 255) & ~(size_t)255;
        return q;
    };
    int*   mode    = (int*)  carve(256);
    bf16*  h_bf    = (bf16*) carve((size_t)N * 128 * 2);
    float* zf      = (float*)carve((size_t)N * 160 * 4);
    bf16*  zh      = (bf16*) carve((size_t)N * 160 * 2);
    float* lin     = (float*)carve((size_t)N * 160 * 4);
    float* el      = (float*)carve((size_t)N * 4 * 4);
    float* er      = (float*)carve((size_t)N * 4 * 4);
    float* wbuf    = (float*)carve((size_t)E * 4 * 4);
    float* sbuf    = (float*)carve((size_t)N * 4 * 4);
    float* bnbuf   = (float*)carve(256 * 4);
    int*   counts  = (int*)  carve((size_t)N * 4);
    int*   row_ptr = (int*)  carve((size_t)(N + 1) * 4);
    int*   cursor  = (int*)  carve((size_t)N * 4);
    int2*  spair   = (int2*) carve((size_t)E * 8);
    bf16*  Wt      = (bf16*) carve((size_t)2 * 160 * 128 * 2);
    float* W32[23];
    for (int i = 3; i < 23; i++) W32[i] = (float*)carve((size_t)in_sizes[i] * 4);

    // staging
    k_probe<<<1, 64, 0, stream>>>(d_in[0], mode);
    k_stage_bf<<<(N * 128 + 255) / 256, 256, 0, stream>>>(d_in[0], h_bf, N * 128, mode);
    for (int i = 3; i < 23; i++) {
        int n = in_sizes[i];
        k_stage<<<(n + 255) / 256, 256, 0, stream>>>(d_in[i], W32[i], n, mode);
    }

    const float* Wc[3] = {W32[3],  W32[8],  W32[13]};
    const float* al[3] = {W32[4],  W32[9],  W32[14]};
    const float* ar[3] = {W32[5],  W32[10], W32[15]};
    const float* bc[3] = {W32[6],  W32[11], W32[16]};
    const float* Wl[3] = {W32[7],  W32[12], W32[17]};
    const float* g0 = W32[18];
    const float* b0 = W32[19];
    const float* g1 = W32[20];
    const float* b1 = W32[21];
    const float* bias_last = W32[22];

    const int E4 = E * 4;
    const int EB4 = (E4 + 255) / 256;
    const int EB = (E + 255) / 256;
    const int GB_ROWS = (N + 63) / 64;
    const int NODE_BLK = (N + 3) / 4;

    // CSR by dst (shared across layers)
    k_zero<<<(N + 255) / 256, 256, 0, stream>>>((float*)counts, N);
    k_hist<<<EB, 256, 0, stream>>>(dst, counts, E);
    k_scan<<<1, 1024, 0, stream>>>(counts, row_ptr, cursor, N);
    k_scatter<<<EB, 256, 0, stream>>>(src, dst, cursor, spair, E);

    // ---- layers 0 and 1 (HC=128, D=32) ----
    for (int l = 0; l < 2; l++) {
        k_wt<128><<<(2 * 128 * 128 + 255) / 256, 256, 0, stream>>>(Wc[l], Wl[l], Wt);
        k_gemm_mfma<128><<<dim3(GB_ROWS, 4), 256, 0, stream>>>(h_bf, Wt, zf, zh, lin, N);
        k_elr<128, 32><<<(N * 4 + 255) / 256, 256, 0, stream>>>(zf, al[l], ar[l], el, er, N);
        k_zero<<<(N * 4 + 255) / 256, 256, 0, stream>>>(sbuf, N * 4);
        k_att1<<<EB4, 256, 0, stream>>>(src, dst, el, er, wbuf, sbuf, E4);
        k_gather<128, 32><<<NODE_BLK, 256, 0, stream>>>(row_ptr, spair, wbuf, sbuf, bc[l], zh, lin, N);
        k_zero<<<1, 256, 0, stream>>>(bnbuf, 256);
        k_bn_stats<<<2048, 128, 0, stream>>>(lin, bnbuf, bnbuf + 128, N);
        const float* gg = (l == 0) ? g0 : g1;
        const float* bb = (l == 0) ? b0 : b1;
        k_bn_apply<<<(N * 128 + 255) / 256, 256, 0, stream>>>(lin, bnbuf, bnbuf + 128, gg, bb, h_bf, N);
    }

    // ---- layer 2 (HC=160, D=40) ----
    k_wt<160><<<(2 * 160 * 128 + 255) / 256, 256, 0, stream>>>(Wc[2], Wl[2], Wt);
    k_gemm_mfma<160><<<dim3(GB_ROWS, 5), 256, 0, stream>>>(h_bf, Wt, zf, zh, lin, N);
    k_elr<160, 40><<<(N * 4 + 255) / 256, 256, 0, stream>>>(zf, al[2], ar[2], el, er, N);
    k_zero<<<(N * 4 + 255) / 256, 256, 0, stream>>>(sbuf, N * 4);
    k_att1<<<EB4, 256, 0, stream>>>(src, dst, el, er, wbuf, sbuf, E4);
    k_gather<160, 40><<<NODE_BLK, 256, 0, stream>>>(row_ptr, spair, wbuf, sbuf, bc[2], zh, lin, N);
    k_out<<<(N * 40 + 255) / 256, 256, 0, stream>>>(lin, bias_last, out, N);
}

// Round 8
// 788.697 us; speedup vs baseline: 3.6202x; 1.3448x over previous
//
#include <hip/hip_runtime.h>
#include <hip/hip_bf16.h>

typedef __hip_bfloat16 bf16;
typedef __attribute__((ext_vector_type(8))) short short8;   // 8 bf16 = 4 VGPRs
typedef __attribute__((ext_vector_type(4))) float f32x4;

__device__ __forceinline__ float b2f(bf16 x) { return __bfloat162float(x); }

// ---------------- dtype probe (inputs proven fp32; kept as cheap insurance) ----------------
__global__ __launch_bounds__(64) void k_probe(const void* __restrict__ feat, int* __restrict__ mode) {
    const bf16* p = (const bf16*)feat;
    int lane = threadIdx.x;
    float m = 0.f;
    for (int i = lane; i < 2048; i += 64) {
        float v = fabsf(b2f(p[2 * i]));
        if (!(v < 1e30f)) v = 1e30f;
        m = fmaxf(m, v);
    }
    #pragma unroll
    for (int off = 32; off > 0; off >>= 1) m = fmaxf(m, __shfl_xor(m, off, 64));
    if (lane == 0) *mode = (m > 1e8f) ? 1 : 0;   // 1 = inputs are fp32
}

// stage feat -> bf16 (GEMM A operand)
__global__ __launch_bounds__(256) void k_stage_bf(const void* __restrict__ in, bf16* __restrict__ out,
                                                  int n, const int* __restrict__ mode) {
    int t = blockIdx.x * 256 + threadIdx.x;
    if (t >= n) return;
    if (*mode) out[t] = __float2bfloat16(((const float*)in)[t]);
    else       out[t] = ((const bf16*)in)[t];
}

// all 20 weight tensors in one launch: block b handles segment b
struct StageDesc { const void* src; float* dst; int n; };
struct StageArgs { StageDesc d[20]; };
__global__ __launch_bounds__(256) void k_stage_all(StageArgs args, const int* __restrict__ mode) {
    const StageDesc sd = args.d[blockIdx.x];
    int m = *mode;
    for (int t = threadIdx.x; t < sd.n; t += 256) {
        float v = m ? ((const float*)sd.src)[t] : b2f(((const bf16*)sd.src)[t]);
        sd.dst[t] = v;
    }
}

__global__ __launch_bounds__(256) void k_zero(float* __restrict__ p, int n) {
    int t = blockIdx.x * 256 + threadIdx.x;
    if (t < n) p[t] = 0.f;
}

// ---------------- CSR build (by dst) ----------------

__global__ __launch_bounds__(256) void k_hist(const int* __restrict__ dst, int* __restrict__ counts, int e) {
    int t = blockIdx.x * 256 + threadIdx.x;
    if (t < e) atomicAdd(&counts[dst[t]], 1);
}

__global__ __launch_bounds__(1024) void k_scan(const int* __restrict__ counts, int* __restrict__ row_ptr,
                                               int* __restrict__ cursor, int n) {
    __shared__ int wsum[16];
    __shared__ int carry_s;
    int lane = threadIdx.x & 63, w = threadIdx.x >> 6;
    if (threadIdx.x == 0) carry_s = 0;
    __syncthreads();
    for (int base = 0; base < n; base += 1024) {
        int i = base + (int)threadIdx.x;
        int v = (i < n) ? counts[i] : 0;
        int x = v;
        #pragma unroll
        for (int off = 1; off < 64; off <<= 1) {
            int t = __shfl_up(x, off, 64);
            if (lane >= off) x += t;
        }
        if (lane == 63) wsum[w] = x;
        __syncthreads();
        if (w == 0 && lane < 16) {
            int s = wsum[lane];
            #pragma unroll
            for (int off = 1; off < 16; off <<= 1) {
                int t = __shfl_up(s, off, 64);
                if (lane >= off) s += t;
            }
            wsum[lane] = s;
        }
        __syncthreads();
        int carry = carry_s;
        int woff = (w == 0) ? 0 : wsum[w - 1];
        int excl = carry + woff + x - v;
        if (i < n) { row_ptr[i] = excl; cursor[i] = excl; }
        __syncthreads();
        if (threadIdx.x == 0) carry_s = carry + wsum[15];
        __syncthreads();
    }
    if (threadIdx.x == 0) row_ptr[n] = carry_s;
}

__global__ __launch_bounds__(256) void k_scatter(const int* __restrict__ src, const int* __restrict__ dst,
                                                 int* __restrict__ cursor, int* __restrict__ ssrc, int e) {
    int t = blockIdx.x * 256 + threadIdx.x;
    if (t < e) {
        int d = dst[t];
        int idx = atomicAdd(&cursor[d], 1);
        ssrc[idx] = src[t];
    }
}

// ---------------- weight transpose+cast: Wt[c][k] = bf16([Wc|Wl][k][c]) ----------------
template <int HC>
__global__ __launch_bounds__(256) void k_wt(const float* __restrict__ Wc, const float* __restrict__ Wl,
                                            bf16* __restrict__ Wt) {
    int t = blockIdx.x * 256 + threadIdx.x;
    if (t >= 2 * HC * 128) return;
    int k = t & 127, c = t >> 7;
    float v = (c < HC) ? Wc[k * HC + c] : Wl[k * HC + c - HC];
    Wt[(size_t)c * 128 + k] = __float2bfloat16(v);
}

// ---------------- MFMA GEMM: A[N,128]bf16 @ Wt[2HC,128]bf16 -> Zh bf16 | Lin f32 ----------------
template <int HC>
__global__ __launch_bounds__(256) void k_gemm_mfma(const bf16* __restrict__ A, const bf16* __restrict__ Wt,
                                                   bf16* __restrict__ Zh, float* __restrict__ Lin, int n) {
    int tid = threadIdx.x;
    int wv = tid >> 6, lane = tid & 63;
    int quad = lane >> 4, m16 = lane & 15;
    int row0 = blockIdx.x * 64 + wv * 16;
    int col0 = blockIdx.y * 64;
    f32x4 acc[4] = {};
    int ar = row0 + m16;
    if (ar >= n) ar = n - 1;
    const short8* Arow = (const short8*)(A + (size_t)ar * 128);
    #pragma unroll
    for (int k8 = 0; k8 < 16; k8 += 4) {
        short8 a = Arow[k8 + quad];
        #pragma unroll
        for (int c = 0; c < 4; c++) {
            const short8* Brow = (const short8*)(Wt + (size_t)(col0 + c * 16 + m16) * 128);
            short8 b = Brow[k8 + quad];
            acc[c] = __builtin_amdgcn_mfma_f32_16x16x32_bf16(a, b, acc[c], 0, 0, 0);
        }
    }
    #pragma unroll
    for (int c = 0; c < 4; c++) {
        int gc = col0 + c * 16 + m16;
        #pragma unroll
        for (int reg = 0; reg < 4; reg++) {
            int r = row0 + quad * 4 + reg;
            if (r >= n) continue;
            float v = acc[c][reg];
            if (gc < HC) Zh[(size_t)r * HC + gc] = __float2bfloat16(v);
            else         Lin[(size_t)r * HC + gc - HC] = v;
        }
    }
}

// ---------------- el/er from bf16 Z ----------------
template <int HC, int D>
__global__ __launch_bounds__(256) void k_elr(const bf16* __restrict__ Z, const float* __restrict__ al,
                                             const float* __restrict__ ar, float* __restrict__ el,
                                             float* __restrict__ er, int n) {
    int t = blockIdx.x * 256 + threadIdx.x;
    if (t >= n * 4) return;
    int node = t >> 2, h = t & 3;
    const __hip_bfloat162* zp = (const __hip_bfloat162*)(Z + (size_t)node * HC + h * D);
    const float* alp = al + h * D;
    const float* arp = ar + h * D;
    float sl = 0.f, sr = 0.f;
    #pragma unroll
    for (int d2 = 0; d2 < D / 2; d2++) {
        __hip_bfloat162 z = zp[d2];
        float zx = b2f(z.x), zy = b2f(z.y);
        sl += zx * alp[2 * d2] + zy * alp[2 * d2 + 1];
        sr += zx * arp[2 * d2] + zy * arp[2 * d2 + 1];
    }
    el[t] = sl;
    er[t] = sr;
}

// ---------------- fused wave-per-node edge softmax + gather ----------------
// Y[node] += (1/ssum) * sum_e exp(leaky(el[src_e]+er[node])) * Z[src_e] + bc
template <int HC, int D>
__global__ __launch_bounds__(256) void k_gather(const int* __restrict__ row_ptr, const int* __restrict__ ssrc,
                                                const float* __restrict__ el, const float* __restrict__ er,
                                                const float* __restrict__ bc, const bf16* __restrict__ Z,
                                                float* __restrict__ Y, int n) {
    constexpr int VP2 = HC / 2;            // bf16 pairs per row; D even => pair never straddles heads
    int node = (int)((blockIdx.x * blockDim.x + threadIdx.x) >> 6);
    int lane = threadIdx.x & 63;
    if (node >= n) return;
    int beg = row_ptr[node], end = row_ptr[node + 1];
    float4 er4 = ((const float4*)er)[node];
    float era[4] = {er4.x, er4.y, er4.z, er4.w};
    const int h0 = (2 * lane) / D;
    const bool has1 = (VP2 > 64) && (lane < VP2 - 64);
    const int h1 = (VP2 > 64) ? (2 * (lane + 64)) / D : 0;
    const float er_0 = era[h0];
    const float er_1 = era[h1];
    float2 a0 = {0.f, 0.f}, a1 = {0.f, 0.f};
    float ss0 = 0.f, ss1 = 0.f;
    const float4* el4p = (const float4*)el;
    for (int base = beg; base < end; base += 64) {
        int cnt = end - base; if (cnt > 64) cnt = 64;
        int my = (base + lane < end) ? ssrc[base + lane] : 0;   // one coalesced load per 64 edges
        #pragma unroll 2
        for (int j = 0; j < cnt; j++) {
            int s = __shfl(my, j, 64);                          // VALU broadcast, no global load
            float4 el4 = el4p[s];                               // 16B broadcast load
            const __hip_bfloat162* zr = (const __hip_bfloat162*)(Z + (size_t)s * HC);
            __hip_bfloat162 z0 = zr[lane];                      // 256B coalesced row load
            float ela[4] = {el4.x, el4.y, el4.z, el4.w};
            float x0 = ela[h0] + er_0;
            x0 = x0 > 0.f ? x0 : 0.2f * x0;
            float w0 = __expf(x0);
            ss0 += w0;
            a0.x += w0 * b2f(z0.x);
            a0.y += w0 * b2f(z0.y);
            if (has1) {
                __hip_bfloat162 z1 = zr[lane + 64];
                float x1 = ela[h1] + er_1;
                x1 = x1 > 0.f ? x1 : 0.2f * x1;
                float w1 = __expf(x1);
                ss1 += w1;
                a1.x += w1 * b2f(z1.x);
                a1.y += w1 * b2f(z1.y);
            }
        }
    }
    float inv0 = (end > beg) ? 1.f / ss0 : 0.f;
    float inv1 = (end > beg && has1) ? 1.f / ss1 : 0.f;
    float2* Y2 = (float2*)(Y + (size_t)node * HC);
    const float2* bc2 = (const float2*)bc;
    float2 y0 = Y2[lane], b0v = bc2[lane];
    y0.x += a0.x * inv0 + b0v.x;
    y0.y += a0.y * inv0 + b0v.y;
    Y2[lane] = y0;
    if (has1) {
        float2 y1 = Y2[lane + 64], b1v = bc2[lane + 64];
        y1.x += a1.x * inv1 + b1v.x;
        y1.y += a1.y * inv1 + b1v.y;
        Y2[lane + 64] = y1;
    }
}

// ---------------- BatchNorm ----------------

__global__ __launch_bounds__(128) void k_bn_stats(const float* __restrict__ Y, float* __restrict__ sum,
                                                  float* __restrict__ sumsq, int n) {
    int c = threadIdx.x;
    float s = 0.f, ss = 0.f;
    for (int r = blockIdx.x; r < n; r += gridDim.x) {
        float v = Y[r * 128 + c];
        s += v;
        ss += v * v;
    }
    atomicAdd(&sum[c], s);
    atomicAdd(&sumsq[c], ss);
}

// BN + ReLU -> bf16 (next layer's GEMM A operand)
__global__ __launch_bounds__(256) void k_bn_apply(const float* __restrict__ Y, const float* __restrict__ sum,
                                                  const float* __restrict__ sumsq, const float* __restrict__ g,
                                                  const float* __restrict__ b, bf16* __restrict__ out, int n) {
    int t = blockIdx.x * 256 + threadIdx.x;
    if (t >= n * 128) return;
    int c = t & 127;
    float invn = 1.f / (float)n;
    float mu = sum[c] * invn;
    float var = sumsq[c] * invn - mu * mu;
    float v = (Y[t] - mu) * rsqrtf(var + 1e-5f) * g[c] + b[c];
    out[t] = __float2bfloat16(v > 0.f ? v : 0.f);
}

// ---------------- final: mean over heads + bias -> fp32 ----------------

__global__ __launch_bounds__(256) void k_out(const float* __restrict__ Y, const float* __restrict__ bias,
                                             float* __restrict__ out, int n) {
    int t = blockIdx.x * 256 + threadIdx.x;
    if (t >= n * 40) return;
    int node = t / 40, c = t - node * 40;
    const float* y = Y + (size_t)node * 160;
    out[t] = 0.25f * (y[c] + y[40 + c] + y[80 + c] + y[120 + c]) + bias[c];
}

// ---------------- launch ----------------

extern "C" void kernel_launch(void* const* d_in, const int* in_sizes, int n_in,
                              void* d_out, int out_size, void* d_ws, size_t ws_size,
                              hipStream_t stream) {
    (void)n_in; (void)out_size; (void)ws_size;
    const int N = in_sizes[0] / 128;
    const int E = in_sizes[1];

    const int* src = (const int*)d_in[1];
    const int* dst = (const int*)d_in[2];
    float* out = (float*)d_out;

    char* p = (char*)d_ws;
    auto carve = [&](size_t bytes) {
        void* q = (void*)p;
        p += (bytes + 255) & ~(size_t)255;
        return q;
    };
    int*   mode    = (int*)  carve(256);
    bf16*  h_bf    = (bf16*) carve((size_t)N * 128 * 2);
    bf16*  zh      = (bf16*) carve((size_t)N * 160 * 2);
    float* lin     = (float*)carve((size_t)N * 160 * 4);
    float* el      = (float*)carve((size_t)N * 4 * 4);
    float* er      = (float*)carve((size_t)N * 4 * 4);
    float* bnbuf   = (float*)carve(256 * 4);
    int*   counts  = (int*)  carve((size_t)N * 4);
    int*   row_ptr = (int*)  carve((size_t)(N + 1) * 4);
    int*   cursor  = (int*)  carve((size_t)N * 4);
    int*   ssrc    = (int*)  carve((size_t)E * 4);
    bf16*  Wt      = (bf16*) carve((size_t)2 * 160 * 128 * 2);
    float* W32[23];
    for (int i = 3; i < 23; i++) W32[i] = (float*)carve((size_t)in_sizes[i] * 4);

    // staging
    k_probe<<<1, 64, 0, stream>>>(d_in[0], mode);
    k_stage_bf<<<(N * 128 + 255) / 256, 256, 0, stream>>>(d_in[0], h_bf, N * 128, mode);
    StageArgs sa;
    for (int i = 3; i < 23; i++) sa.d[i - 3] = StageDesc{d_in[i], W32[i], in_sizes[i]};
    k_stage_all<<<20, 256, 0, stream>>>(sa, mode);

    const float* Wc[3] = {W32[3],  W32[8],  W32[13]};
    const float* al[3] = {W32[4],  W32[9],  W32[14]};
    const float* ar[3] = {W32[5],  W32[10], W32[15]};
    const float* bc[3] = {W32[6],  W32[11], W32[16]};
    const float* Wl[3] = {W32[7],  W32[12], W32[17]};
    const float* g0 = W32[18];
    const float* b0 = W32[19];
    const float* g1 = W32[20];
    const float* b1 = W32[21];
    const float* bias_last = W32[22];

    const int EB = (E + 255) / 256;
    const int GB_ROWS = (N + 63) / 64;
    const int NODE_BLK = (N + 3) / 4;

    // CSR by dst (shared across layers)
    k_zero<<<(N + 255) / 256, 256, 0, stream>>>((float*)counts, N);
    k_hist<<<EB, 256, 0, stream>>>(dst, counts, E);
    k_scan<<<1, 1024, 0, stream>>>(counts, row_ptr, cursor, N);
    k_scatter<<<EB, 256, 0, stream>>>(src, dst, cursor, ssrc, E);

    // ---- layers 0 and 1 (HC=128, D=32) ----
    for (int l = 0; l < 2; l++) {
        k_wt<128><<<(2 * 128 * 128 + 255) / 256, 256, 0, stream>>>(Wc[l], Wl[l], Wt);
        k_gemm_mfma<128><<<dim3(GB_ROWS, 4), 256, 0, stream>>>(h_bf, Wt, zh, lin, N);
        k_elr<128, 32><<<(N * 4 + 255) / 256, 256, 0, stream>>>(zh, al[l], ar[l], el, er, N);
        k_gather<128, 32><<<NODE_BLK, 256, 0, stream>>>(row_ptr, ssrc, el, er, bc[l], zh, lin, N);
        k_zero<<<1, 256, 0, stream>>>(bnbuf, 256);
        k_bn_stats<<<2048, 128, 0, stream>>>(lin, bnbuf, bnbuf + 128, N);
        const float* gg = (l == 0) ? g0 : g1;
        const float* bb = (l == 0) ? b0 : b1;
        k_bn_apply<<<(N * 128 + 255) / 256, 256, 0, stream>>>(lin, bnbuf, bnbuf + 128, gg, bb, h_bf, N);
    }

    // ---- layer 2 (HC=160, D=40) ----
    k_wt<160><<<(2 * 160 * 128 + 255) / 256, 256, 0, stream>>>(Wc[2], Wl[2], Wt);
    k_gemm_mfma<160><<<dim3(GB_ROWS, 5), 256, 0, stream>>>(h_bf, Wt, zh, lin, N);
    k_elr<160, 40><<<(N * 4 + 255) / 256, 256, 0, stream>>>(zh, al[2], ar[2], el, er, N);
    k_gather<160, 40><<<NODE_BLK, 256, 0, stream>>>(row_ptr, ssrc, el, er, bc[2], zh, lin, N);
    k_out<<<(N * 40 + 255) / 256, 256, 0, stream>>>(lin, bias_last, out, N);
}

// Round 10
// 752.744 us; speedup vs baseline: 3.7931x; 1.0478x over previous
//
#include <hip/hip_runtime.h>
#include <hip/hip_bf16.h>

typedef __hip_bfloat16 bf16;
typedef __attribute__((ext_vector_type(8))) short short8;   // 8 bf16 = 4 VGPRs
typedef __attribute__((ext_vector_type(4))) float f32x4;

__device__ __forceinline__ float b2f(bf16 x) { return __bfloat162float(x); }
__device__ __forceinline__ float bits2f(unsigned short u) {
    return __uint_as_float(((unsigned)u) << 16);
}

// ---------------- dtype probe (inputs proven fp32; kept as cheap insurance) ----------------
__global__ __launch_bounds__(64) void k_probe(const void* __restrict__ feat, int* __restrict__ mode) {
    const bf16* p = (const bf16*)feat;
    int lane = threadIdx.x;
    float m = 0.f;
    for (int i = lane; i < 2048; i += 64) {
        float v = fabsf(b2f(p[2 * i]));
        if (!(v < 1e30f)) v = 1e30f;
        m = fmaxf(m, v);
    }
    #pragma unroll
    for (int off = 32; off > 0; off >>= 1) m = fmaxf(m, __shfl_xor(m, off, 64));
    if (lane == 0) *mode = (m > 1e8f) ? 1 : 0;   // 1 = inputs are fp32
}

// stage feat -> bf16 (GEMM A operand)
__global__ __launch_bounds__(256) void k_stage_bf(const void* __restrict__ in, bf16* __restrict__ out,
                                                  int n, const int* __restrict__ mode) {
    int t = blockIdx.x * 256 + threadIdx.x;
    if (t >= n) return;
    if (*mode) out[t] = __float2bfloat16(((const float*)in)[t]);
    else       out[t] = ((const bf16*)in)[t];
}

// all 20 weight tensors in one launch: block b handles segment b
struct StageDesc { const void* src; float* dst; int n; };
struct StageArgs { StageDesc d[20]; };
__global__ __launch_bounds__(256) void k_stage_all(StageArgs args, const int* __restrict__ mode) {
    const StageDesc sd = args.d[blockIdx.x];
    int m = *mode;
    for (int t = threadIdx.x; t < sd.n; t += 256) {
        float v = m ? ((const float*)sd.src)[t] : b2f(((const bf16*)sd.src)[t]);
        sd.dst[t] = v;
    }
}

// zero counts[N] and bn partial buffers (both layers)
__global__ __launch_bounds__(256) void k_zero_all(int* __restrict__ counts, float* __restrict__ bn0,
                                                  float* __restrict__ bn1, int n) {
    int t = blockIdx.x * 256 + threadIdx.x;
    if (t < n) counts[t] = 0;
    if (t < 256) { bn0[t] = 0.f; bn1[t] = 0.f; }
}

// ---------------- CSR build (by dst) ----------------

__global__ __launch_bounds__(256) void k_hist(const int* __restrict__ dst, int* __restrict__ counts, int e) {
    int t = blockIdx.x * 256 + threadIdx.x;
    if (t < e) atomicAdd(&counts[dst[t]], 1);
}

__global__ __launch_bounds__(1024) void k_scan(const int* __restrict__ counts, int* __restrict__ row_ptr,
                                               int* __restrict__ cursor, int n) {
    __shared__ int wsum[16];
    __shared__ int carry_s;
    int lane = threadIdx.x & 63, w = threadIdx.x >> 6;
    if (threadIdx.x == 0) carry_s = 0;
    __syncthreads();
    for (int base = 0; base < n; base += 1024) {
        int i = base + (int)threadIdx.x;
        int v = (i < n) ? counts[i] : 0;
        int x = v;
        #pragma unroll
        for (int off = 1; off < 64; off <<= 1) {
            int t = __shfl_up(x, off, 64);
            if (lane >= off) x += t;
        }
        if (lane == 63) wsum[w] = x;
        __syncthreads();
        if (w == 0 && lane < 16) {
            int s = wsum[lane];
            #pragma unroll
            for (int off = 1; off < 16; off <<= 1) {
                int t = __shfl_up(s, off, 64);
                if (lane >= off) s += t;
            }
            wsum[lane] = s;
        }
        __syncthreads();
        int carry = carry_s;
        int woff = (w == 0) ? 0 : wsum[w - 1];
        int excl = carry + woff + x - v;
        if (i < n) { row_ptr[i] = excl; cursor[i] = excl; }
        __syncthreads();
        if (threadIdx.x == 0) carry_s = carry + wsum[15];
        __syncthreads();
    }
    if (threadIdx.x == 0) row_ptr[n] = carry_s;
}

__global__ __launch_bounds__(256) void k_scatter(const int* __restrict__ src, const int* __restrict__ dst,
                                                 int* __restrict__ cursor, int* __restrict__ ssrc, int e) {
    int t = blockIdx.x * 256 + threadIdx.x;
    if (t < e) {
        int d = dst[t];
        int idx = atomicAdd(&cursor[d], 1);
        ssrc[idx] = src[t];
    }
}

// ---------------- all 3 layers' weight transpose+cast in one launch ----------------
__global__ __launch_bounds__(256) void k_wt_all(const float* __restrict__ Wc0, const float* __restrict__ Wl0,
                                                const float* __restrict__ Wc1, const float* __restrict__ Wl1,
                                                const float* __restrict__ Wc2, const float* __restrict__ Wl2,
                                                bf16* __restrict__ Wt0, bf16* __restrict__ Wt1,
                                                bf16* __restrict__ Wt2) {
    int t = blockIdx.x * 256 + threadIdx.x;
    const float* Wc; const float* Wl; bf16* Wt; int HC;
    if (t < 32768)       { Wc = Wc0; Wl = Wl0; Wt = Wt0; HC = 128; }
    else if (t < 65536)  { t -= 32768; Wc = Wc1; Wl = Wl1; Wt = Wt1; HC = 128; }
    else if (t < 106496) { t -= 65536; Wc = Wc2; Wl = Wl2; Wt = Wt2; HC = 160; }
    else return;
    int k = t & 127, c = t >> 7;
    float v = (c < HC) ? Wc[k * HC + c] : Wl[k * HC + c - HC];
    Wt[(size_t)c * 128 + k] = __float2bfloat16(v);
}

// ---------------- MFMA GEMM: A[N,128]bf16 @ Wt[2HC,128]bf16 -> Zh bf16 | Lin f32 ----------------
template <int HC>
__global__ __launch_bounds__(256) void k_gemm_mfma(const bf16* __restrict__ A, const bf16* __restrict__ Wt,
                                                   bf16* __restrict__ Zh, float* __restrict__ Lin, int n) {
    int tid = threadIdx.x;
    int wv = tid >> 6, lane = tid & 63;
    int quad = lane >> 4, m16 = lane & 15;
    int row0 = blockIdx.x * 64 + wv * 16;
    int col0 = blockIdx.y * 64;
    f32x4 acc[4] = {};
    int ar = row0 + m16;
    if (ar >= n) ar = n - 1;
    const short8* Arow = (const short8*)(A + (size_t)ar * 128);
    #pragma unroll
    for (int k8 = 0; k8 < 16; k8 += 4) {
        short8 a = Arow[k8 + quad];
        #pragma unroll
        for (int c = 0; c < 4; c++) {
            const short8* Brow = (const short8*)(Wt + (size_t)(col0 + c * 16 + m16) * 128);
            short8 b = Brow[k8 + quad];
            acc[c] = __builtin_amdgcn_mfma_f32_16x16x32_bf16(a, b, acc[c], 0, 0, 0);
        }
    }
    #pragma unroll
    for (int c = 0; c < 4; c++) {
        int gc = col0 + c * 16 + m16;
        #pragma unroll
        for (int reg = 0; reg < 4; reg++) {
            int r = row0 + quad * 4 + reg;
            if (r >= n) continue;
            float v = acc[c][reg];
            if (gc < HC) Zh[(size_t)r * HC + gc] = __float2bfloat16(v);
            else         Lin[(size_t)r * HC + gc - HC] = v;
        }
    }
}

// ---------------- el/er from bf16 Z ----------------
template <int HC, int D>
__global__ __launch_bounds__(256) void k_elr(const bf16* __restrict__ Z, const float* __restrict__ al,
                                             const float* __restrict__ ar, float* __restrict__ el,
                                             float* __restrict__ er, int n) {
    int t = blockIdx.x * 256 + threadIdx.x;
    if (t >= n * 4) return;
    int node = t >> 2, h = t & 3;
    const __hip_bfloat162* zp = (const __hip_bfloat162*)(Z + (size_t)node * HC + h * D);
    const float* alp = al + h * D;
    const float* arp = ar + h * D;
    float sl = 0.f, sr = 0.f;
    #pragma unroll
    for (int d2 = 0; d2 < D / 2; d2++) {
        __hip_bfloat162 z = zp[d2];
        float zx = b2f(z.x), zy = b2f(z.y);
        sl += zx * alp[2 * d2] + zy * alp[2 * d2 + 1];
        sr += zx * arp[2 * d2] + zy * arp[2 * d2 + 1];
    }
    el[t] = sl;
    er[t] = sr;
}

// ---------------- fused edge softmax + gather, quarter-wave per edge ----------------
// wave = node; each 16-lane quarter processes one edge; lane covers DPL = HC/16 dims.
// Head for lane: hq = t16>>2 (holds for both (128,32) and (160,40)).
// Within a head group (4 lanes sharing hq), w values are IDENTICAL per edge — so the
// per-head denominator needs reduction over quarter bits {16,32} ONLY (bits {0,1}
// would over-count 4x — that was round 9's bug).
template <int HC, int D>
__global__ __launch_bounds__(256) void k_gather(const int* __restrict__ row_ptr, const int* __restrict__ ssrc,
                                                const float* __restrict__ el, const float* __restrict__ er,
                                                const float* __restrict__ bc, const bf16* __restrict__ Z,
                                                float* __restrict__ Y, int n) {
    constexpr int DPL = HC / 16;           // 8 (HC=128) or 10 (HC=160)
    int node = (int)((blockIdx.x * blockDim.x + threadIdx.x) >> 6);
    int lane = threadIdx.x & 63;
    if (node >= n) return;
    int q16 = lane & 48;                   // quarter base lane
    int t16 = lane & 15;
    int beg = row_ptr[node], end = row_ptr[node + 1];
    int hq = t16 >> 2;                     // head for this lane's dims
    float er_h = er[node * 4 + hq];
    float acc[DPL];
    #pragma unroll
    for (int k = 0; k < DPL; k++) acc[k] = 0.f;
    float ss = 0.f;
    for (int base = beg; base < end; base += 64) {
        int my = (base + lane < end) ? ssrc[base + lane] : 0;   // one coalesced idx load / 64 edges
        #pragma unroll 4
        for (int j = 0; j < 16; j++) {
            int pos = base + q16 + j;
            if (pos >= end) break;
            int s = __shfl(my, q16 + j, 64);
            float x = el[s * 4 + hq] + er_h;                    // 4B broadcast within head group
            x = x > 0.f ? x : 0.2f * x;
            float w = __expf(x);
            ss += w;
            if constexpr (DPL == 8) {
                short8 z8 = *(const short8*)(Z + (size_t)s * HC + t16 * 8);   // 16B aligned
                #pragma unroll
                for (int k = 0; k < 8; k++)
                    acc[k] += w * bits2f((unsigned short)z8[k]);
            } else {
                const __hip_bfloat162* z2 = (const __hip_bfloat162*)(Z + (size_t)s * HC + t16 * DPL);
                #pragma unroll
                for (int k2 = 0; k2 < DPL / 2; k2++) {
                    __hip_bfloat162 z = z2[k2];
                    acc[2 * k2]     += w * b2f(z.x);
                    acc[2 * k2 + 1] += w * b2f(z.y);
                }
            }
        }
    }
    // reduce acc across quarters (lanes sharing t16)
    #pragma unroll
    for (int k = 0; k < DPL; k++) {
        acc[k] += __shfl_xor(acc[k], 16, 64);
        acc[k] += __shfl_xor(acc[k], 32, 64);
    }
    // per-head denominator: cross-quarter reduction only (head-group lanes hold identical copies)
    ss += __shfl_xor(ss, 16, 64);
    ss += __shfl_xor(ss, 32, 64);
    if (q16 == 0) {
        float inv = (end > beg) ? 1.f / ss : 0.f;
        float* yr = Y + (size_t)node * HC + t16 * DPL;
        const float* bcr = bc + t16 * DPL;
        #pragma unroll
        for (int k = 0; k < DPL; k++) yr[k] += acc[k] * inv + bcr[k];
    }
}

// ---------------- BatchNorm ----------------

__global__ __launch_bounds__(128) void k_bn_stats(const float* __restrict__ Y, float* __restrict__ sum,
                                                  float* __restrict__ sumsq, int n) {
    int c = threadIdx.x;
    float s = 0.f, ss = 0.f;
    for (int r = blockIdx.x; r < n; r += gridDim.x) {
        float v = Y[r * 128 + c];
        s += v;
        ss += v * v;
    }
    atomicAdd(&sum[c], s);
    atomicAdd(&sumsq[c], ss);
}

// BN + ReLU -> bf16 (next layer's GEMM A operand)
__global__ __launch_bounds__(256) void k_bn_apply(const float* __restrict__ Y, const float* __restrict__ sum,
                                                  const float* __restrict__ sumsq, const float* __restrict__ g,
                                                  const float* __restrict__ b, bf16* __restrict__ out, int n) {
    int t = blockIdx.x * 256 + threadIdx.x;
    if (t >= n * 128) return;
    int c = t & 127;
    float invn = 1.f / (float)n;
    float mu = sum[c] * invn;
    float var = sumsq[c] * invn - mu * mu;
    float v = (Y[t] - mu) * rsqrtf(var + 1e-5f) * g[c] + b[c];
    out[t] = __float2bfloat16(v > 0.f ? v : 0.f);
}

// ---------------- final: mean over heads + bias -> fp32 ----------------

__global__ __launch_bounds__(256) void k_out(const float* __restrict__ Y, const float* __restrict__ bias,
                                             float* __restrict__ out, int n) {
    int t = blockIdx.x * 256 + threadIdx.x;
    if (t >= n * 40) return;
    int node = t / 40, c = t - node * 40;
    const float* y = Y + (size_t)node * 160;
    out[t] = 0.25f * (y[c] + y[40 + c] + y[80 + c] + y[120 + c]) + bias[c];
}

// ---------------- launch ----------------

extern "C" void kernel_launch(void* const* d_in, const int* in_sizes, int n_in,
                              void* d_out, int out_size, void* d_ws, size_t ws_size,
                              hipStream_t stream) {
    (void)n_in; (void)out_size; (void)ws_size;
    const int N = in_sizes[0] / 128;
    const int E = in_sizes[1];

    const int* src = (const int*)d_in[1];
    const int* dst = (const int*)d_in[2];
    float* out = (float*)d_out;

    char* p = (char*)d_ws;
    auto carve = [&](size_t bytes) {
        void* q = (void*)p;
        p += (bytes + 255) & ~(size_t)255;
        return q;
    };
    int*   mode    = (int*)  carve(256);
    bf16*  h_bf    = (bf16*) carve((size_t)N * 128 * 2);
    bf16*  zh      = (bf16*) carve((size_t)N * 160 * 2);
    float* lin     = (float*)carve((size_t)N * 160 * 4);
    float* el      = (float*)carve((size_t)N * 4 * 4);
    float* er      = (float*)carve((size_t)N * 4 * 4);
    float* bn0     = (float*)carve(256 * 4);
    float* bn1     = (float*)carve(256 * 4);
    int*   counts  = (int*)  carve((size_t)N * 4);
    int*   row_ptr = (int*)  carve((size_t)(N + 1) * 4);
    int*   cursor  = (int*)  carve((size_t)N * 4);
    int*   ssrc    = (int*)  carve((size_t)E * 4);
    bf16*  Wt0     = (bf16*) carve((size_t)2 * 128 * 128 * 2);
    bf16*  Wt1     = (bf16*) carve((size_t)2 * 128 * 128 * 2);
    bf16*  Wt2     = (bf16*) carve((size_t)2 * 160 * 128 * 2);
    float* W32[23];
    for (int i = 3; i < 23; i++) W32[i] = (float*)carve((size_t)in_sizes[i] * 4);

    // staging
    k_probe<<<1, 64, 0, stream>>>(d_in[0], mode);
    k_stage_bf<<<(N * 128 + 255) / 256, 256, 0, stream>>>(d_in[0], h_bf, N * 128, mode);
    StageArgs sa;
    for (int i = 3; i < 23; i++) sa.d[i - 3] = StageDesc{d_in[i], W32[i], in_sizes[i]};
    k_stage_all<<<20, 256, 0, stream>>>(sa, mode);

    const float* Wc[3] = {W32[3],  W32[8],  W32[13]};
    const float* al[3] = {W32[4],  W32[9],  W32[14]};
    const float* ar[3] = {W32[5],  W32[10], W32[15]};
    const float* bc[3] = {W32[6],  W32[11], W32[16]};
    const float* Wl[3] = {W32[7],  W32[12], W32[17]};
    const float* g0 = W32[18];
    const float* b0 = W32[19];
    const float* g1 = W32[20];
    const float* b1 = W32[21];
    const float* bias_last = W32[22];

    k_wt_all<<<(106496 + 255) / 256, 256, 0, stream>>>(Wc[0], Wl[0], Wc[1], Wl[1], Wc[2], Wl[2],
                                                       Wt0, Wt1, Wt2);
    bf16* Wt[3] = {Wt0, Wt1, Wt2};

    const int EB = (E + 255) / 256;
    const int GB_ROWS = (N + 63) / 64;
    const int NODE_BLK = (N + 3) / 4;

    // CSR by dst (shared across layers) + bn buffer zeroing
    k_zero_all<<<(N + 255) / 256, 256, 0, stream>>>(counts, bn0, bn1, N);
    k_hist<<<EB, 256, 0, stream>>>(dst, counts, E);
    k_scan<<<1, 1024, 0, stream>>>(counts, row_ptr, cursor, N);
    k_scatter<<<EB, 256, 0, stream>>>(src, dst, cursor, ssrc, E);

    // ---- layers 0 and 1 (HC=128, D=32) ----
    for (int l = 0; l < 2; l++) {
        float* bnb = (l == 0) ? bn0 : bn1;
        k_gemm_mfma<128><<<dim3(GB_ROWS, 4), 256, 0, stream>>>(h_bf, Wt[l], zh, lin, N);
        k_elr<128, 32><<<(N * 4 + 255) / 256, 256, 0, stream>>>(zh, al[l], ar[l], el, er, N);
        k_gather<128, 32><<<NODE_BLK, 256, 0, stream>>>(row_ptr, ssrc, el, er, bc[l], zh, lin, N);
        k_bn_stats<<<2048, 128, 0, stream>>>(lin, bnb, bnb + 128, N);
        const float* gg = (l == 0) ? g0 : g1;
        const float* bb = (l == 0) ? b0 : b1;
        k_bn_apply<<<(N * 128 + 255) / 256, 256, 0, stream>>>(lin, bnb, bnb + 128, gg, bb, h_bf, N);
    }

    // ---- layer 2 (HC=160, D=40) ----
    k_gemm_mfma<160><<<dim3(GB_ROWS, 5), 256, 0, stream>>>(h_bf, Wt[2], zh, lin, N);
    k_elr<160, 40><<<(N * 4 + 255) / 256, 256, 0, stream>>>(zh, al[2], ar[2], el, er, N);
    k_gather<160, 40><<<NODE_BLK, 256, 0, stream>>>(row_ptr, ssrc, el, er, bc[2], zh, lin, N);
    k_out<<<(N * 40 + 255) / 256, 256, 0, stream>>>(lin, bias_last, out, N);
}

// Round 12
// 685.846 us; speedup vs baseline: 4.1630x; 1.0975x over previous
//
#include <hip/hip_runtime.h>
#include <hip/hip_bf16.h>

typedef __hip_bfloat16 bf16;
typedef __attribute__((ext_vector_type(8))) short short8;   // 8 bf16 = 4 VGPRs
typedef __attribute__((ext_vector_type(4))) float f32x4;

__device__ __forceinline__ float b2f(bf16 x) { return __bfloat162float(x); }
__device__ __forceinline__ float bits2f(unsigned short u) {
    return __uint_as_float(((unsigned)u) << 16);
}

// ---------------- dtype probe (inputs proven fp32; kept as cheap insurance) ----------------
__global__ __launch_bounds__(64) void k_probe(const void* __restrict__ feat, int* __restrict__ mode) {
    const bf16* p = (const bf16*)feat;
    int lane = threadIdx.x;
    float m = 0.f;
    for (int i = lane; i < 2048; i += 64) {
        float v = fabsf(b2f(p[2 * i]));
        if (!(v < 1e30f)) v = 1e30f;
        m = fmaxf(m, v);
    }
    #pragma unroll
    for (int off = 32; off > 0; off >>= 1) m = fmaxf(m, __shfl_xor(m, off, 64));
    if (lane == 0) *mode = (m > 1e8f) ? 1 : 0;   // 1 = inputs are fp32
}

// stage feat -> bf16 (GEMM A operand)
__global__ __launch_bounds__(256) void k_stage_bf(const void* __restrict__ in, bf16* __restrict__ out,
                                                  int n, const int* __restrict__ mode) {
    int t = blockIdx.x * 256 + threadIdx.x;
    if (t >= n) return;
    if (*mode) out[t] = __float2bfloat16(((const float*)in)[t]);
    else       out[t] = ((const bf16*)in)[t];
}

// all 20 weight tensors in one launch: block b handles segment b
struct StageDesc { const void* src; float* dst; int n; };
struct StageArgs { StageDesc d[20]; };
__global__ __launch_bounds__(256) void k_stage_all(StageArgs args, const int* __restrict__ mode) {
    const StageDesc sd = args.d[blockIdx.x];
    int m = *mode;
    for (int t = threadIdx.x; t < sd.n; t += 256) {
        float v = m ? ((const float*)sd.src)[t] : b2f(((const bf16*)sd.src)[t]);
        sd.dst[t] = v;
    }
}

// zero counts[N] and bn partial buffers (both layers)
__global__ __launch_bounds__(256) void k_zero_all(int* __restrict__ counts, float* __restrict__ bn0,
                                                  float* __restrict__ bn1, int n) {
    int t = blockIdx.x * 256 + threadIdx.x;
    if (t < n) counts[t] = 0;
    if (t < 256) { bn0[t] = 0.f; bn1[t] = 0.f; }
}

// ---------------- CSR build (by dst) ----------------

__global__ __launch_bounds__(256) void k_hist(const int* __restrict__ dst, int* __restrict__ counts, int e) {
    int t = blockIdx.x * 256 + threadIdx.x;
    if (t < e) atomicAdd(&counts[dst[t]], 1);
}

// round-10 proven block-strided scan
__global__ __launch_bounds__(1024) void k_scan(const int* __restrict__ counts, int* __restrict__ row_ptr,
                                               int* __restrict__ cursor, int n) {
    __shared__ int wsum[16];
    __shared__ int carry_s;
    int lane = threadIdx.x & 63, w = threadIdx.x >> 6;
    if (threadIdx.x == 0) carry_s = 0;
    __syncthreads();
    for (int base = 0; base < n; base += 1024) {
        int i = base + (int)threadIdx.x;
        int v = (i < n) ? counts[i] : 0;
        int x = v;
        #pragma unroll
        for (int off = 1; off < 64; off <<= 1) {
            int t = __shfl_up(x, off, 64);
            if (lane >= off) x += t;
        }
        if (lane == 63) wsum[w] = x;
        __syncthreads();
        if (w == 0 && lane < 16) {
            int s = wsum[lane];
            #pragma unroll
            for (int off = 1; off < 16; off <<= 1) {
                int t = __shfl_up(s, off, 64);
                if (lane >= off) s += t;
            }
            wsum[lane] = s;
        }
        __syncthreads();
        int carry = carry_s;
        int woff = (w == 0) ? 0 : wsum[w - 1];
        int excl = carry + woff + x - v;
        if (i < n) { row_ptr[i] = excl; cursor[i] = excl; }
        __syncthreads();
        if (threadIdx.x == 0) carry_s = carry + wsum[15];
        __syncthreads();
    }
    if (threadIdx.x == 0) row_ptr[n] = carry_s;
}

__global__ __launch_bounds__(256) void k_scatter(const int* __restrict__ src, const int* __restrict__ dst,
                                                 int* __restrict__ cursor, int* __restrict__ ssrc, int e) {
    int t = blockIdx.x * 256 + threadIdx.x;
    if (t < e) {
        int d = dst[t];
        int idx = atomicAdd(&cursor[d], 1);
        ssrc[idx] = src[t];
    }
}

// ---------------- all 3 layers' weight transpose+cast in one launch ----------------
__global__ __launch_bounds__(256) void k_wt_all(const float* __restrict__ Wc0, const float* __restrict__ Wl0,
                                                const float* __restrict__ Wc1, const float* __restrict__ Wl1,
                                                const float* __restrict__ Wc2, const float* __restrict__ Wl2,
                                                bf16* __restrict__ Wt0, bf16* __restrict__ Wt1,
                                                bf16* __restrict__ Wt2) {
    int t = blockIdx.x * 256 + threadIdx.x;
    const float* Wc; const float* Wl; bf16* Wt; int HC;
    if (t < 32768)       { Wc = Wc0; Wl = Wl0; Wt = Wt0; HC = 128; }
    else if (t < 65536)  { t -= 32768; Wc = Wc1; Wl = Wl1; Wt = Wt1; HC = 128; }
    else if (t < 106496) { t -= 65536; Wc = Wc2; Wl = Wl2; Wt = Wt2; HC = 160; }
    else return;
    int k = t & 127, c = t >> 7;
    float v = (c < HC) ? Wc[k * HC + c] : Wl[k * HC + c - HC];
    Wt[(size_t)c * 128 + k] = __float2bfloat16(v);
}

// ---------------- MFMA GEMM: A[N,128]bf16 @ Wt[2HC,128]bf16 -> Zh bf16 | Lin f32 ----------------
template <int HC>
__global__ __launch_bounds__(256) void k_gemm_mfma(const bf16* __restrict__ A, const bf16* __restrict__ Wt,
                                                   bf16* __restrict__ Zh, float* __restrict__ Lin, int n) {
    int tid = threadIdx.x;
    int wv = tid >> 6, lane = tid & 63;
    int quad = lane >> 4, m16 = lane & 15;
    int row0 = blockIdx.x * 64 + wv * 16;
    int col0 = blockIdx.y * 64;
    f32x4 acc[4] = {};
    int ar = row0 + m16;
    if (ar >= n) ar = n - 1;
    const short8* Arow = (const short8*)(A + (size_t)ar * 128);
    #pragma unroll
    for (int k8 = 0; k8 < 16; k8 += 4) {
        short8 a = Arow[k8 + quad];
        #pragma unroll
        for (int c = 0; c < 4; c++) {
            const short8* Brow = (const short8*)(Wt + (size_t)(col0 + c * 16 + m16) * 128);
            short8 b = Brow[k8 + quad];
            acc[c] = __builtin_amdgcn_mfma_f32_16x16x32_bf16(a, b, acc[c], 0, 0, 0);
        }
    }
    #pragma unroll
    for (int c = 0; c < 4; c++) {
        int gc = col0 + c * 16 + m16;
        #pragma unroll
        for (int reg = 0; reg < 4; reg++) {
            int r = row0 + quad * 4 + reg;
            if (r >= n) continue;
            float v = acc[c][reg];
            if (gc < HC) Zh[(size_t)r * HC + gc] = __float2bfloat16(v);
            else         Lin[(size_t)r * HC + gc - HC] = v;
        }
    }
}

// ---------------- el/er from bf16 Z ----------------
template <int HC, int D>
__global__ __launch_bounds__(256) void k_elr(const bf16* __restrict__ Z, const float* __restrict__ al,
                                             const float* __restrict__ ar, float* __restrict__ el,
                                             float* __restrict__ er, int n) {
    int t = blockIdx.x * 256 + threadIdx.x;
    if (t >= n * 4) return;
    int node = t >> 2, h = t & 3;
    const __hip_bfloat162* zp = (const __hip_bfloat162*)(Z + (size_t)node * HC + h * D);
    const float* alp = al + h * D;
    const float* arp = ar + h * D;
    float sl = 0.f, sr = 0.f;
    #pragma unroll
    for (int d2 = 0; d2 < D / 2; d2++) {
        __hip_bfloat162 z = zp[d2];
        float zx = b2f(z.x), zy = b2f(z.y);
        sl += zx * alp[2 * d2] + zy * alp[2 * d2 + 1];
        sr += zx * arp[2 * d2] + zy * arp[2 * d2 + 1];
    }
    el[t] = sl;
    er[t] = sr;
}

// ---------------- fused edge softmax + gather, quarter-wave per edge (interleaved) ----------------
// wave = node. Quarter q processes edges base+q+4j. Trip count is WAVE-UNIFORM
// ((cnt+3)>>2 for every lane): positions sl >= cnt contribute zero automatically
// because their source lanes preloaded w0..w3 = 0 (and s_my = 0, a harmless
// in-bounds row-0 load). No divergent loop exits => no shfl-from-masked-lane hazard.
// Denominator: head-group lanes hold identical ss; reduce over quarter bits {16,32} only.
// LAST: fuse head-mean + bias -> out (Y read-only = lin).
template <int HC, int D, bool LAST>
__global__ __launch_bounds__(256) void k_gather(const int* __restrict__ row_ptr, const int* __restrict__ ssrc,
                                                const float* __restrict__ el, const float* __restrict__ er,
                                                const float* __restrict__ bc, const bf16* __restrict__ Z,
                                                float* __restrict__ Y, const float* __restrict__ bias,
                                                float* __restrict__ out, int n) {
    constexpr int DPL = HC / 16;           // 8 (HC=128) or 10 (HC=160)
    int node = (int)((blockIdx.x * blockDim.x + threadIdx.x) >> 6);
    int lane = threadIdx.x & 63;
    if (node >= n) return;
    int qi = lane >> 4;
    int t16 = lane & 15;
    int hq = t16 >> 2;
    int beg = row_ptr[node], end = row_ptr[node + 1];
    float4 er4 = ((const float4*)er)[node];
    const float4* el4p = (const float4*)el;
    const bf16* Zt = Z + t16 * DPL;
    float acc[DPL];
    #pragma unroll
    for (int k = 0; k < DPL; k++) acc[k] = 0.f;
    float ss = 0.f;
    for (int base = beg; base < end; base += 64) {
        int idx = base + lane;
        bool valid = idx < end;
        int s_my = valid ? ssrc[idx] : 0;          // coalesced
        float4 e4 = el4p[s_my];                    // one random 16B per lane, issued together
        float x0 = e4.x + er4.x; x0 = x0 > 0.f ? x0 : 0.2f * x0;
        float x1 = e4.y + er4.y; x1 = x1 > 0.f ? x1 : 0.2f * x1;
        float x2 = e4.z + er4.z; x2 = x2 > 0.f ? x2 : 0.2f * x2;
        float x3 = e4.w + er4.w; x3 = x3 > 0.f ? x3 : 0.2f * x3;
        float w0 = valid ? __expf(x0) : 0.f;
        float w1 = valid ? __expf(x1) : 0.f;
        float w2 = valid ? __expf(x2) : 0.f;
        float w3 = valid ? __expf(x3) : 0.f;
        int cnt = end - base; if (cnt > 64) cnt = 64;
        int iters = (cnt + 3) >> 2;                // wave-uniform trip count
        for (int j = 0; j < iters; j++) {
            int sl = qi + (j << 2);                // may exceed cnt-1: w's are 0 there
            int s = __shfl(s_my, sl, 64);
            float a0 = __shfl(w0, sl, 64);
            float a1 = __shfl(w1, sl, 64);
            float a2 = __shfl(w2, sl, 64);
            float a3 = __shfl(w3, sl, 64);
            float wv = (hq & 2) ? ((hq & 1) ? a3 : a2) : ((hq & 1) ? a1 : a0);
            ss += wv;
            const bf16* zr = Zt + (size_t)s * HC;
            if constexpr (DPL == 8) {
                short8 z8 = *(const short8*)zr;    // 16B aligned
                #pragma unroll
                for (int k = 0; k < 8; k++)
                    acc[k] += wv * bits2f((unsigned short)z8[k]);
            } else {
                const __hip_bfloat162* z2 = (const __hip_bfloat162*)zr;
                #pragma unroll
                for (int k2 = 0; k2 < DPL / 2; k2++) {
                    __hip_bfloat162 z = z2[k2];
                    acc[2 * k2]     += wv * b2f(z.x);
                    acc[2 * k2 + 1] += wv * b2f(z.y);
                }
            }
        }
    }
    // cross-quarter reductions (butterfly => all lanes hold totals)
    #pragma unroll
    for (int k = 0; k < DPL; k++) {
        acc[k] += __shfl_xor(acc[k], 16, 64);
        acc[k] += __shfl_xor(acc[k], 32, 64);
    }
    ss += __shfl_xor(ss, 16, 64);
    ss += __shfl_xor(ss, 32, 64);
    float inv = (end > beg) ? 1.f / ss : 0.f;
    if constexpr (!LAST) {
        if ((lane & 48) == 0) {
            float* yr = Y + (size_t)node * HC + t16 * DPL;
            const float* bcr = bc + t16 * DPL;
            #pragma unroll
            for (int k = 0; k < DPL; k++) yr[k] += acc[k] * inv + bcr[k];
        }
    } else {
        // yv = agg + bc + lin; head-mean over lane bits {4,8}; write out + bias
        float yv[DPL];
        const float* lr = Y + (size_t)node * HC + t16 * DPL;   // Y = lin (read-only)
        const float* bcr = bc + t16 * DPL;
        #pragma unroll
        for (int k = 0; k < DPL; k++) yv[k] = acc[k] * inv + bcr[k] + lr[k];
        #pragma unroll
        for (int k = 0; k < DPL; k++) {
            yv[k] += __shfl_xor(yv[k], 4, 64);
            yv[k] += __shfl_xor(yv[k], 8, 64);
        }
        if (lane < 4) {
            float* orow = out + (size_t)node * 40 + t16 * DPL;
            const float* br = bias + t16 * DPL;
            #pragma unroll
            for (int k = 0; k < DPL; k++) orow[k] = 0.25f * yv[k] + br[k];
        }
    }
}

// ---------------- BatchNorm ----------------

__global__ __launch_bounds__(128) void k_bn_stats(const float* __restrict__ Y, float* __restrict__ sum,
                                                  float* __restrict__ sumsq, int n) {
    int c = threadIdx.x;
    float s = 0.f, ss = 0.f;
    for (int r = blockIdx.x; r < n; r += gridDim.x) {
        float v = Y[r * 128 + c];
        s += v;
        ss += v * v;
    }
    atomicAdd(&sum[c], s);
    atomicAdd(&sumsq[c], ss);
}

// BN + ReLU -> bf16 (next layer's GEMM A operand)
__global__ __launch_bounds__(256) void k_bn_apply(const float* __restrict__ Y, const float* __restrict__ sum,
                                                  const float* __restrict__ sumsq, const float* __restrict__ g,
                                                  const float* __restrict__ b, bf16* __restrict__ out, int n) {
    int t = blockIdx.x * 256 + threadIdx.x;
    if (t >= n * 128) return;
    int c = t & 127;
    float invn = 1.f / (float)n;
    float mu = sum[c] * invn;
    float var = sumsq[c] * invn - mu * mu;
    float v = (Y[t] - mu) * rsqrtf(var + 1e-5f) * g[c] + b[c];
    out[t] = __float2bfloat16(v > 0.f ? v : 0.f);
}

// ---------------- launch ----------------

extern "C" void kernel_launch(void* const* d_in, const int* in_sizes, int n_in,
                              void* d_out, int out_size, void* d_ws, size_t ws_size,
                              hipStream_t stream) {
    (void)n_in; (void)out_size; (void)ws_size;
    const int N = in_sizes[0] / 128;
    const int E = in_sizes[1];

    const int* src = (const int*)d_in[1];
    const int* dst = (const int*)d_in[2];
    float* out = (float*)d_out;

    char* p = (char*)d_ws;
    auto carve = [&](size_t bytes) {
        void* q = (void*)p;
        p += (bytes + 255) & ~(size_t)255;
        return q;
    };
    int*   mode    = (int*)  carve(256);
    bf16*  h_bf    = (bf16*) carve((size_t)N * 128 * 2);
    bf16*  zh      = (bf16*) carve((size_t)N * 160 * 2);
    float* lin     = (float*)carve((size_t)N * 160 * 4);
    float* el      = (float*)carve((size_t)N * 4 * 4);
    float* er      = (float*)carve((size_t)N * 4 * 4);
    float* bn0     = (float*)carve(256 * 4);
    float* bn1     = (float*)carve(256 * 4);
    int*   counts  = (int*)  carve((size_t)N * 4);
    int*   row_ptr = (int*)  carve((size_t)(N + 1) * 4);
    int*   cursor  = (int*)  carve((size_t)N * 4);
    int*   ssrc    = (int*)  carve((size_t)E * 4);
    bf16*  Wt0     = (bf16*) carve((size_t)2 * 128 * 128 * 2);
    bf16*  Wt1     = (bf16*) carve((size_t)2 * 128 * 128 * 2);
    bf16*  Wt2     = (bf16*) carve((size_t)2 * 160 * 128 * 2);
    float* W32[23];
    for (int i = 3; i < 23; i++) W32[i] = (float*)carve((size_t)in_sizes[i] * 4);

    // staging
    k_probe<<<1, 64, 0, stream>>>(d_in[0], mode);
    k_stage_bf<<<(N * 128 + 255) / 256, 256, 0, stream>>>(d_in[0], h_bf, N * 128, mode);
    StageArgs sa;
    for (int i = 3; i < 23; i++) sa.d[i - 3] = StageDesc{d_in[i], W32[i], in_sizes[i]};
    k_stage_all<<<20, 256, 0, stream>>>(sa, mode);

    const float* Wc[3] = {W32[3],  W32[8],  W32[13]};
    const float* al[3] = {W32[4],  W32[9],  W32[14]};
    const float* ar[3] = {W32[5],  W32[10], W32[15]};
    const float* bc[3] = {W32[6],  W32[11], W32[16]};
    const float* Wl[3] = {W32[7],  W32[12], W32[17]};
    const float* g0 = W32[18];
    const float* b0 = W32[19];
    const float* g1 = W32[20];
    const float* b1 = W32[21];
    const float* bias_last = W32[22];

    k_wt_all<<<(106496 + 255) / 256, 256, 0, stream>>>(Wc[0], Wl[0], Wc[1], Wl[1], Wc[2], Wl[2],
                                                       Wt0, Wt1, Wt2);
    bf16* Wt[3] = {Wt0, Wt1, Wt2};

    const int EB = (E + 255) / 256;
    const int GB_ROWS = (N + 63) / 64;
    const int NODE_BLK = (N + 3) / 4;

    // CSR by dst (shared across layers) + bn buffer zeroing
    k_zero_all<<<(N + 255) / 256, 256, 0, stream>>>(counts, bn0, bn1, N);
    k_hist<<<EB, 256, 0, stream>>>(dst, counts, E);
    k_scan<<<1, 1024, 0, stream>>>(counts, row_ptr, cursor, N);
    k_scatter<<<EB, 256, 0, stream>>>(src, dst, cursor, ssrc, E);

    // ---- layers 0 and 1 (HC=128, D=32) ----
    for (int l = 0; l < 2; l++) {
        float* bnb = (l == 0) ? bn0 : bn1;
        k_gemm_mfma<128><<<dim3(GB_ROWS, 4), 256, 0, stream>>>(h_bf, Wt[l], zh, lin, N);
        k_elr<128, 32><<<(N * 4 + 255) / 256, 256, 0, stream>>>(zh, al[l], ar[l], el, er, N);
        k_gather<128, 32, false><<<NODE_BLK, 256, 0, stream>>>(row_ptr, ssrc, el, er, bc[l], zh,
                                                               lin, nullptr, nullptr, N);
        k_bn_stats<<<2048, 128, 0, stream>>>(lin, bnb, bnb + 128, N);
        const float* gg = (l == 0) ? g0 : g1;
        const float* bb = (l == 0) ? b0 : b1;
        k_bn_apply<<<(N * 128 + 255) / 256, 256, 0, stream>>>(lin, bnb, bnb + 128, gg, bb, h_bf, N);
    }

    // ---- layer 2 (HC=160, D=40), k_out fused into gather ----
    k_gemm_mfma<160><<<dim3(GB_ROWS, 5), 256, 0, stream>>>(h_bf, Wt[2], zh, lin, N);
    k_elr<160, 40><<<(N * 4 + 255) / 256, 256, 0, stream>>>(zh, al[2], ar[2], el, er, N);
    k_gather<160, 40, true><<<NODE_BLK, 256, 0, stream>>>(row_ptr, ssrc, el, er, bc[2], zh,
                                                          lin, bias_last, out, N);
}

// Round 13
// 677.252 us; speedup vs baseline: 4.2159x; 1.0127x over previous
//
#include <hip/hip_runtime.h>
#include <hip/hip_bf16.h>

typedef __hip_bfloat16 bf16;
typedef __attribute__((ext_vector_type(8))) short short8;   // 8 bf16 = 4 VGPRs
typedef __attribute__((ext_vector_type(4))) float f32x4;

__device__ __forceinline__ float b2f(bf16 x) { return __bfloat162float(x); }
__device__ __forceinline__ float bits2f(unsigned short u) {
    return __uint_as_float(((unsigned)u) << 16);
}

// ---------------- dtype probe (inputs proven fp32; kept as cheap insurance) ----------------
__global__ __launch_bounds__(64) void k_probe(const void* __restrict__ feat, int* __restrict__ mode) {
    const bf16* p = (const bf16*)feat;
    int lane = threadIdx.x;
    float m = 0.f;
    for (int i = lane; i < 2048; i += 64) {
        float v = fabsf(b2f(p[2 * i]));
        if (!(v < 1e30f)) v = 1e30f;
        m = fmaxf(m, v);
    }
    #pragma unroll
    for (int off = 32; off > 0; off >>= 1) m = fmaxf(m, __shfl_xor(m, off, 64));
    if (lane == 0) *mode = (m > 1e8f) ? 1 : 0;   // 1 = inputs are fp32
}

// stage feat -> bf16, 4 elements/thread (float4 in, short4 out)
__global__ __launch_bounds__(256) void k_stage_bf(const void* __restrict__ in, bf16* __restrict__ out,
                                                  int n4, const int* __restrict__ mode) {
    int t = blockIdx.x * 256 + threadIdx.x;
    if (t >= n4) return;
    if (*mode) {
        float4 v = ((const float4*)in)[t];
        union { bf16 h[4]; short4 s; } u;
        u.h[0] = __float2bfloat16(v.x);
        u.h[1] = __float2bfloat16(v.y);
        u.h[2] = __float2bfloat16(v.z);
        u.h[3] = __float2bfloat16(v.w);
        ((short4*)out)[t] = u.s;
    } else {
        ((short4*)out)[t] = ((const short4*)in)[t];
    }
}

// all 20 weight tensors in one launch: block b handles segment b
struct StageDesc { const void* src; float* dst; int n; };
struct StageArgs { StageDesc d[20]; };
__global__ __launch_bounds__(256) void k_stage_all(StageArgs args, const int* __restrict__ mode) {
    const StageDesc sd = args.d[blockIdx.x];
    int m = *mode;
    for (int t = threadIdx.x; t < sd.n; t += 256) {
        float v = m ? ((const float*)sd.src)[t] : b2f(((const bf16*)sd.src)[t]);
        sd.dst[t] = v;
    }
}

// zero counts[N] and bn partial buffers (both layers)
__global__ __launch_bounds__(256) void k_zero_all(int* __restrict__ counts, float* __restrict__ bn0,
                                                  float* __restrict__ bn1, int n) {
    int t = blockIdx.x * 256 + threadIdx.x;
    if (t < n) counts[t] = 0;
    if (t < 256) { bn0[t] = 0.f; bn1[t] = 0.f; }
}

// ---------------- CSR build (by dst) ----------------

__global__ __launch_bounds__(256) void k_hist(const int* __restrict__ dst, int* __restrict__ counts, int e) {
    int t = blockIdx.x * 256 + threadIdx.x;
    if (t < e) atomicAdd(&counts[dst[t]], 1);
}

// round-10 proven block-strided scan
__global__ __launch_bounds__(1024) void k_scan(const int* __restrict__ counts, int* __restrict__ row_ptr,
                                               int* __restrict__ cursor, int n) {
    __shared__ int wsum[16];
    __shared__ int carry_s;
    int lane = threadIdx.x & 63, w = threadIdx.x >> 6;
    if (threadIdx.x == 0) carry_s = 0;
    __syncthreads();
    for (int base = 0; base < n; base += 1024) {
        int i = base + (int)threadIdx.x;
        int v = (i < n) ? counts[i] : 0;
        int x = v;
        #pragma unroll
        for (int off = 1; off < 64; off <<= 1) {
            int t = __shfl_up(x, off, 64);
            if (lane >= off) x += t;
        }
        if (lane == 63) wsum[w] = x;
        __syncthreads();
        if (w == 0 && lane < 16) {
            int s = wsum[lane];
            #pragma unroll
            for (int off = 1; off < 16; off <<= 1) {
                int t = __shfl_up(s, off, 64);
                if (lane >= off) s += t;
            }
            wsum[lane] = s;
        }
        __syncthreads();
        int carry = carry_s;
        int woff = (w == 0) ? 0 : wsum[w - 1];
        int excl = carry + woff + x - v;
        if (i < n) { row_ptr[i] = excl; cursor[i] = excl; }
        __syncthreads();
        if (threadIdx.x == 0) carry_s = carry + wsum[15];
        __syncthreads();
    }
    if (threadIdx.x == 0) row_ptr[n] = carry_s;
}

__global__ __launch_bounds__(256) void k_scatter(const int* __restrict__ src, const int* __restrict__ dst,
                                                 int* __restrict__ cursor, int* __restrict__ ssrc, int e) {
    int t = blockIdx.x * 256 + threadIdx.x;
    if (t < e) {
        int d = dst[t];
        int idx = atomicAdd(&cursor[d], 1);
        ssrc[idx] = src[t];
    }
}

// ---------------- all 3 layers' weight transpose+cast in one launch ----------------
__global__ __launch_bounds__(256) void k_wt_all(const float* __restrict__ Wc0, const float* __restrict__ Wl0,
                                                const float* __restrict__ Wc1, const float* __restrict__ Wl1,
                                                const float* __restrict__ Wc2, const float* __restrict__ Wl2,
                                                bf16* __restrict__ Wt0, bf16* __restrict__ Wt1,
                                                bf16* __restrict__ Wt2) {
    int t = blockIdx.x * 256 + threadIdx.x;
    const float* Wc; const float* Wl; bf16* Wt; int HC;
    if (t < 32768)       { Wc = Wc0; Wl = Wl0; Wt = Wt0; HC = 128; }
    else if (t < 65536)  { t -= 32768; Wc = Wc1; Wl = Wl1; Wt = Wt1; HC = 128; }
    else if (t < 106496) { t -= 65536; Wc = Wc2; Wl = Wl2; Wt = Wt2; HC = 160; }
    else return;
    int k = t & 127, c = t >> 7;
    float v = (c < HC) ? Wc[k * HC + c] : Wl[k * HC + c - HC];
    Wt[(size_t)c * 128 + k] = __float2bfloat16(v);
}

// ---------------- MFMA GEMM: A[N,128]bf16 @ Wt[2HC,128]bf16 -> Zh bf16 | Lin f32 ----------------
template <int HC>
__global__ __launch_bounds__(256) void k_gemm_mfma(const bf16* __restrict__ A, const bf16* __restrict__ Wt,
                                                   bf16* __restrict__ Zh, float* __restrict__ Lin, int n) {
    int tid = threadIdx.x;
    int wv = tid >> 6, lane = tid & 63;
    int quad = lane >> 4, m16 = lane & 15;
    int row0 = blockIdx.x * 64 + wv * 16;
    int col0 = blockIdx.y * 64;
    f32x4 acc[4] = {};
    int ar = row0 + m16;
    if (ar >= n) ar = n - 1;
    const short8* Arow = (const short8*)(A + (size_t)ar * 128);
    #pragma unroll
    for (int k8 = 0; k8 < 16; k8 += 4) {
        short8 a = Arow[k8 + quad];
        #pragma unroll
        for (int c = 0; c < 4; c++) {
            const short8* Brow = (const short8*)(Wt + (size_t)(col0 + c * 16 + m16) * 128);
            short8 b = Brow[k8 + quad];
            acc[c] = __builtin_amdgcn_mfma_f32_16x16x32_bf16(a, b, acc[c], 0, 0, 0);
        }
    }
    #pragma unroll
    for (int c = 0; c < 4; c++) {
        int gc = col0 + c * 16 + m16;
        #pragma unroll
        for (int reg = 0; reg < 4; reg++) {
            int r = row0 + quad * 4 + reg;
            if (r >= n) continue;
            float v = acc[c][reg];
            if (gc < HC) Zh[(size_t)r * HC + gc] = __float2bfloat16(v);
            else         Lin[(size_t)r * HC + gc - HC] = v;
        }
    }
}

// ---------------- el/er from bf16 Z ----------------
template <int HC, int D>
__global__ __launch_bounds__(256) void k_elr(const bf16* __restrict__ Z, const float* __restrict__ al,
                                             const float* __restrict__ ar, float* __restrict__ el,
                                             float* __restrict__ er, int n) {
    int t = blockIdx.x * 256 + threadIdx.x;
    if (t >= n * 4) return;
    int node = t >> 2, h = t & 3;
    const __hip_bfloat162* zp = (const __hip_bfloat162*)(Z + (size_t)node * HC + h * D);
    const float* alp = al + h * D;
    const float* arp = ar + h * D;
    float sl = 0.f, sr = 0.f;
    #pragma unroll
    for (int d2 = 0; d2 < D / 2; d2++) {
        __hip_bfloat162 z = zp[d2];
        float zx = b2f(z.x), zy = b2f(z.y);
        sl += zx * alp[2 * d2] + zy * alp[2 * d2 + 1];
        sr += zx * arp[2 * d2] + zy * arp[2 * d2 + 1];
    }
    el[t] = sl;
    er[t] = sr;
}

// ---------------- fused edge softmax + gather (round-12 proven, unchanged) ----------------
template <int HC, int D, bool LAST>
__global__ __launch_bounds__(256) void k_gather(const int* __restrict__ row_ptr, const int* __restrict__ ssrc,
                                                const float* __restrict__ el, const float* __restrict__ er,
                                                const float* __restrict__ bc, const bf16* __restrict__ Z,
                                                float* __restrict__ Y, const float* __restrict__ bias,
                                                float* __restrict__ out, int n) {
    constexpr int DPL = HC / 16;           // 8 (HC=128) or 10 (HC=160)
    int node = (int)((blockIdx.x * blockDim.x + threadIdx.x) >> 6);
    int lane = threadIdx.x & 63;
    if (node >= n) return;
    int qi = lane >> 4;
    int t16 = lane & 15;
    int hq = t16 >> 2;
    int beg = row_ptr[node], end = row_ptr[node + 1];
    float4 er4 = ((const float4*)er)[node];
    const float4* el4p = (const float4*)el;
    const bf16* Zt = Z + t16 * DPL;
    float acc[DPL];
    #pragma unroll
    for (int k = 0; k < DPL; k++) acc[k] = 0.f;
    float ss = 0.f;
    for (int base = beg; base < end; base += 64) {
        int idx = base + lane;
        bool valid = idx < end;
        int s_my = valid ? ssrc[idx] : 0;          // coalesced
        float4 e4 = el4p[s_my];                    // one random 16B per lane
        float x0 = e4.x + er4.x; x0 = x0 > 0.f ? x0 : 0.2f * x0;
        float x1 = e4.y + er4.y; x1 = x1 > 0.f ? x1 : 0.2f * x1;
        float x2 = e4.z + er4.z; x2 = x2 > 0.f ? x2 : 0.2f * x2;
        float x3 = e4.w + er4.w; x3 = x3 > 0.f ? x3 : 0.2f * x3;
        float w0 = valid ? __expf(x0) : 0.f;
        float w1 = valid ? __expf(x1) : 0.f;
        float w2 = valid ? __expf(x2) : 0.f;
        float w3 = valid ? __expf(x3) : 0.f;
        int cnt = end - base; if (cnt > 64) cnt = 64;
        int iters = (cnt + 3) >> 2;                // wave-uniform trip count
        for (int j = 0; j < iters; j++) {
            int sl = qi + (j << 2);                // may exceed cnt-1: w's are 0 there
            int s = __shfl(s_my, sl, 64);
            float a0 = __shfl(w0, sl, 64);
            float a1 = __shfl(w1, sl, 64);
            float a2 = __shfl(w2, sl, 64);
            float a3 = __shfl(w3, sl, 64);
            float wv = (hq & 2) ? ((hq & 1) ? a3 : a2) : ((hq & 1) ? a1 : a0);
            ss += wv;
            const bf16* zr = Zt + (size_t)s * HC;
            if constexpr (DPL == 8) {
                short8 z8 = *(const short8*)zr;    // 16B aligned
                #pragma unroll
                for (int k = 0; k < 8; k++)
                    acc[k] += wv * bits2f((unsigned short)z8[k]);
            } else {
                const __hip_bfloat162* z2 = (const __hip_bfloat162*)zr;
                #pragma unroll
                for (int k2 = 0; k2 < DPL / 2; k2++) {
                    __hip_bfloat162 z = z2[k2];
                    acc[2 * k2]     += wv * b2f(z.x);
                    acc[2 * k2 + 1] += wv * b2f(z.y);
                }
            }
        }
    }
    #pragma unroll
    for (int k = 0; k < DPL; k++) {
        acc[k] += __shfl_xor(acc[k], 16, 64);
        acc[k] += __shfl_xor(acc[k], 32, 64);
    }
    ss += __shfl_xor(ss, 16, 64);
    ss += __shfl_xor(ss, 32, 64);
    float inv = (end > beg) ? 1.f / ss : 0.f;
    if constexpr (!LAST) {
        if ((lane & 48) == 0) {
            float* yr = Y + (size_t)node * HC + t16 * DPL;
            const float* bcr = bc + t16 * DPL;
            #pragma unroll
            for (int k = 0; k < DPL; k++) yr[k] += acc[k] * inv + bcr[k];
        }
    } else {
        float yv[DPL];
        const float* lr = Y + (size_t)node * HC + t16 * DPL;   // Y = lin (read-only)
        const float* bcr = bc + t16 * DPL;
        #pragma unroll
        for (int k = 0; k < DPL; k++) yv[k] = acc[k] * inv + bcr[k] + lr[k];
        #pragma unroll
        for (int k = 0; k < DPL; k++) {
            yv[k] += __shfl_xor(yv[k], 4, 64);
            yv[k] += __shfl_xor(yv[k], 8, 64);
        }
        if (lane < 4) {
            float* orow = out + (size_t)node * 40 + t16 * DPL;
            const float* br = bias + t16 * DPL;
            #pragma unroll
            for (int k = 0; k < DPL; k++) orow[k] = 0.25f * yv[k] + br[k];
        }
    }
}

// ---------------- BatchNorm stats: float4 loads + LDS reduce + few atomics ----------------
// thread t: channel quad q=(t&31) (channels 4q..4q+3), row group g=(t>>5) of 8.
__global__ __launch_bounds__(256) void k_bn_stats(const float* __restrict__ Y, float* __restrict__ sum,
                                                  float* __restrict__ sumsq, int n) {
    __shared__ float4 lds_s[8][32];
    __shared__ float4 lds_q[8][32];
    int t = threadIdx.x;
    int q = t & 31, g = t >> 5;
    const float4* Y4 = (const float4*)Y;   // row r -> Y4[r*32 + q]
    float4 s = {0.f, 0.f, 0.f, 0.f}, ss = {0.f, 0.f, 0.f, 0.f};
    for (int r = blockIdx.x * 8 + g; r < n; r += gridDim.x * 8) {
        float4 v = Y4[(size_t)r * 32 + q];
        s.x += v.x; s.y += v.y; s.z += v.z; s.w += v.w;
        ss.x += v.x * v.x; ss.y += v.y * v.y; ss.z += v.z * v.z; ss.w += v.w * v.w;
    }
    lds_s[g][q] = s; lds_q[g][q] = ss;
    __syncthreads();
    if (t < 32) {
        float4 S = lds_s[0][t], Q = lds_q[0][t];
        #pragma unroll
        for (int g2 = 1; g2 < 8; g2++) {
            float4 a = lds_s[g2][t], b = lds_q[g2][t];
            S.x += a.x; S.y += a.y; S.z += a.z; S.w += a.w;
            Q.x += b.x; Q.y += b.y; Q.z += b.z; Q.w += b.w;
        }
        atomicAdd(&sum[4 * t + 0], S.x); atomicAdd(&sum[4 * t + 1], S.y);
        atomicAdd(&sum[4 * t + 2], S.z); atomicAdd(&sum[4 * t + 3], S.w);
        atomicAdd(&sumsq[4 * t + 0], Q.x); atomicAdd(&sumsq[4 * t + 1], Q.y);
        atomicAdd(&sumsq[4 * t + 2], Q.z); atomicAdd(&sumsq[4 * t + 3], Q.w);
    }
}

// BN + ReLU -> bf16, 4 channels/thread (float4 in, short4 out)
__global__ __launch_bounds__(256) void k_bn_apply(const float* __restrict__ Y, const float* __restrict__ sum,
                                                  const float* __restrict__ sumsq, const float* __restrict__ g,
                                                  const float* __restrict__ b, bf16* __restrict__ out, int n) {
    int t = blockIdx.x * 256 + threadIdx.x;
    if (t >= n * 32) return;
    int c4 = (t & 31) * 4;
    float4 v = ((const float4*)Y)[t];
    float invn = 1.f / (float)n;
    union { bf16 h[4]; short4 s; } u;
    float vv[4] = {v.x, v.y, v.z, v.w};
    #pragma unroll
    for (int k = 0; k < 4; k++) {
        int c = c4 + k;
        float mu = sum[c] * invn;
        float var = sumsq[c] * invn - mu * mu;
        float r = (vv[k] - mu) * rsqrtf(var + 1e-5f) * g[c] + b[c];
        u.h[k] = __float2bfloat16(r > 0.f ? r : 0.f);
    }
    ((short4*)out)[t] = u.s;
}

// ---------------- launch ----------------

extern "C" void kernel_launch(void* const* d_in, const int* in_sizes, int n_in,
                              void* d_out, int out_size, void* d_ws, size_t ws_size,
                              hipStream_t stream) {
    (void)n_in; (void)out_size; (void)ws_size;
    const int N = in_sizes[0] / 128;
    const int E = in_sizes[1];

    const int* src = (const int*)d_in[1];
    const int* dst = (const int*)d_in[2];
    float* out = (float*)d_out;

    char* p = (char*)d_ws;
    auto carve = [&](size_t bytes) {
        void* q = (void*)p;
        p += (bytes + 255) & ~(size_t)255;
        return q;
    };
    int*   mode    = (int*)  carve(256);
    bf16*  h_bf    = (bf16*) carve((size_t)N * 128 * 2);
    bf16*  zh      = (bf16*) carve((size_t)N * 160 * 2);
    float* lin     = (float*)carve((size_t)N * 160 * 4);
    float* el      = (float*)carve((size_t)N * 4 * 4);
    float* er      = (float*)carve((size_t)N * 4 * 4);
    float* bn0     = (float*)carve(256 * 4);
    float* bn1     = (float*)carve(256 * 4);
    int*   counts  = (int*)  carve((size_t)N * 4);
    int*   row_ptr = (int*)  carve((size_t)(N + 1) * 4);
    int*   cursor  = (int*)  carve((size_t)N * 4);
    int*   ssrc    = (int*)  carve((size_t)E * 4);
    bf16*  Wt0     = (bf16*) carve((size_t)2 * 128 * 128 * 2);
    bf16*  Wt1     = (bf16*) carve((size_t)2 * 128 * 128 * 2);
    bf16*  Wt2     = (bf16*) carve((size_t)2 * 160 * 128 * 2);
    float* W32[23];
    for (int i = 3; i < 23; i++) W32[i] = (float*)carve((size_t)in_sizes[i] * 4);

    // staging
    k_probe<<<1, 64, 0, stream>>>(d_in[0], mode);
    k_stage_bf<<<(N * 32 + 255) / 256, 256, 0, stream>>>(d_in[0], h_bf, N * 32, mode);
    StageArgs sa;
    for (int i = 3; i < 23; i++) sa.d[i - 3] = StageDesc{d_in[i], W32[i], in_sizes[i]};
    k_stage_all<<<20, 256, 0, stream>>>(sa, mode);

    const float* Wc[3] = {W32[3],  W32[8],  W32[13]};
    const float* al[3] = {W32[4],  W32[9],  W32[14]};
    const float* ar[3] = {W32[5],  W32[10], W32[15]};
    const float* bc[3] = {W32[6],  W32[11], W32[16]};
    const float* Wl[3] = {W32[7],  W32[12], W32[17]};
    const float* g0 = W32[18];
    const float* b0 = W32[19];
    const float* g1 = W32[20];
    const float* b1 = W32[21];
    const float* bias_last = W32[22];

    k_wt_all<<<(106496 + 255) / 256, 256, 0, stream>>>(Wc[0], Wl[0], Wc[1], Wl[1], Wc[2], Wl[2],
                                                       Wt0, Wt1, Wt2);
    bf16* Wt[3] = {Wt0, Wt1, Wt2};

    const int EB = (E + 255) / 256;
    const int GB_ROWS = (N + 63) / 64;
    const int NODE_BLK = (N + 3) / 4;

    // CSR by dst (shared across layers) + bn buffer zeroing
    k_zero_all<<<(N + 255) / 256, 256, 0, stream>>>(counts, bn0, bn1, N);
    k_hist<<<EB, 256, 0, stream>>>(dst, counts, E);
    k_scan<<<1, 1024, 0, stream>>>(counts, row_ptr, cursor, N);
    k_scatter<<<EB, 256, 0, stream>>>(src, dst, cursor, ssrc, E);

    // ---- layers 0 and 1 (HC=128, D=32) ----
    for (int l = 0; l < 2; l++) {
        float* bnb = (l == 0) ? bn0 : bn1;
        k_gemm_mfma<128><<<dim3(GB_ROWS, 4), 256, 0, stream>>>(h_bf, Wt[l], zh, lin, N);
        k_elr<128, 32><<<(N * 4 + 255) / 256, 256, 0, stream>>>(zh, al[l], ar[l], el, er, N);
        k_gather<128, 32, false><<<NODE_BLK, 256, 0, stream>>>(row_ptr, ssrc, el, er, bc[l], zh,
                                                               lin, nullptr, nullptr, N);
        k_bn_stats<<<512, 256, 0, stream>>>(lin, bnb, bnb + 128, N);
        const float* gg = (l == 0) ? g0 : g1;
        const float* bb = (l == 0) ? b0 : b1;
        k_bn_apply<<<(N * 32 + 255) / 256, 256, 0, stream>>>(lin, bnb, bnb + 128, gg, bb, h_bf, N);
    }

    // ---- layer 2 (HC=160, D=40), k_out fused into gather ----
    k_gemm_mfma<160><<<dim3(GB_ROWS, 5), 256, 0, stream>>>(h_bf, Wt[2], zh, lin, N);
    k_elr<160, 40><<<(N * 4 + 255) / 256, 256, 0, stream>>>(zh, al[2], ar[2], el, er, N);
    k_gather<160, 40, true><<<NODE_BLK, 256, 0, stream>>>(row_ptr, ssrc, el, er, bc[2], zh,
                                                          lin, bias_last, out, N);
}

// Round 14
// 675.023 us; speedup vs baseline: 4.2298x; 1.0033x over previous
//
#include <hip/hip_runtime.h>
#include <hip/hip_bf16.h>

typedef __hip_bfloat16 bf16;
typedef __attribute__((ext_vector_type(8))) short short8;   // 8 bf16 = 4 VGPRs
typedef __attribute__((ext_vector_type(4))) float f32x4;
typedef __attribute__((ext_vector_type(2))) float f32x2;

__device__ __forceinline__ float b2f(bf16 x) { return __bfloat162float(x); }
__device__ __forceinline__ float bits2f(unsigned short u) {
    return __uint_as_float(((unsigned)u) << 16);
}

// ---------------- dtype probe (inputs proven fp32; kept as cheap insurance) ----------------
__global__ __launch_bounds__(64) void k_probe(const void* __restrict__ feat, int* __restrict__ mode) {
    const bf16* p = (const bf16*)feat;
    int lane = threadIdx.x;
    float m = 0.f;
    for (int i = lane; i < 2048; i += 64) {
        float v = fabsf(b2f(p[2 * i]));
        if (!(v < 1e30f)) v = 1e30f;
        m = fmaxf(m, v);
    }
    #pragma unroll
    for (int off = 32; off > 0; off >>= 1) m = fmaxf(m, __shfl_xor(m, off, 64));
    if (lane == 0) *mode = (m > 1e8f) ? 1 : 0;   // 1 = inputs are fp32
}

// stage feat -> bf16, 4 elements/thread (float4 in, short4 out)
__global__ __launch_bounds__(256) void k_stage_bf(const void* __restrict__ in, bf16* __restrict__ out,
                                                  int n4, const int* __restrict__ mode) {
    int t = blockIdx.x * 256 + threadIdx.x;
    if (t >= n4) return;
    if (*mode) {
        float4 v = ((const float4*)in)[t];
        union { bf16 h[4]; short4 s; } u;
        u.h[0] = __float2bfloat16(v.x);
        u.h[1] = __float2bfloat16(v.y);
        u.h[2] = __float2bfloat16(v.z);
        u.h[3] = __float2bfloat16(v.w);
        ((short4*)out)[t] = u.s;
    } else {
        ((short4*)out)[t] = ((const short4*)in)[t];
    }
}

// all 20 weight tensors; grid (20, 8): x = tensor, y = chunk
struct StageDesc { const void* src; float* dst; int n; };
struct StageArgs { StageDesc d[20]; };
__global__ __launch_bounds__(256) void k_stage_all(StageArgs args, const int* __restrict__ mode) {
    const StageDesc sd = args.d[blockIdx.x];
    int m = *mode;
    for (int t = blockIdx.y * 256 + threadIdx.x; t < sd.n; t += 8 * 256) {
        float v = m ? ((const float*)sd.src)[t] : b2f(((const bf16*)sd.src)[t]);
        sd.dst[t] = v;
    }
}

// zero counts[N] and bn partial buffers (both layers)
__global__ __launch_bounds__(256) void k_zero_all(int* __restrict__ counts, float* __restrict__ bn0,
                                                  float* __restrict__ bn1, int n) {
    int t = blockIdx.x * 256 + threadIdx.x;
    if (t < n) counts[t] = 0;
    if (t < 256) { bn0[t] = 0.f; bn1[t] = 0.f; }
}

// ---------------- CSR build (by dst) ----------------

__global__ __launch_bounds__(256) void k_hist(const int* __restrict__ dst, int* __restrict__ counts, int e) {
    int t = blockIdx.x * 256 + threadIdx.x;
    if (t < e) atomicAdd(&counts[dst[t]], 1);
}

// round-10 proven block-strided scan
__global__ __launch_bounds__(1024) void k_scan(const int* __restrict__ counts, int* __restrict__ row_ptr,
                                               int* __restrict__ cursor, int n) {
    __shared__ int wsum[16];
    __shared__ int carry_s;
    int lane = threadIdx.x & 63, w = threadIdx.x >> 6;
    if (threadIdx.x == 0) carry_s = 0;
    __syncthreads();
    for (int base = 0; base < n; base += 1024) {
        int i = base + (int)threadIdx.x;
        int v = (i < n) ? counts[i] : 0;
        int x = v;
        #pragma unroll
        for (int off = 1; off < 64; off <<= 1) {
            int t = __shfl_up(x, off, 64);
            if (lane >= off) x += t;
        }
        if (lane == 63) wsum[w] = x;
        __syncthreads();
        if (w == 0 && lane < 16) {
            int s = wsum[lane];
            #pragma unroll
            for (int off = 1; off < 16; off <<= 1) {
                int t = __shfl_up(s, off, 64);
                if (lane >= off) s += t;
            }
            wsum[lane] = s;
        }
        __syncthreads();
        int carry = carry_s;
        int woff = (w == 0) ? 0 : wsum[w - 1];
        int excl = carry + woff + x - v;
        if (i < n) { row_ptr[i] = excl; cursor[i] = excl; }
        __syncthreads();
        if (threadIdx.x == 0) carry_s = carry + wsum[15];
        __syncthreads();
    }
    if (threadIdx.x == 0) row_ptr[n] = carry_s;
}

__global__ __launch_bounds__(256) void k_scatter(const int* __restrict__ src, const int* __restrict__ dst,
                                                 int* __restrict__ cursor, int* __restrict__ ssrc, int e) {
    int t = blockIdx.x * 256 + threadIdx.x;
    if (t < e) {
        int d = dst[t];
        int idx = atomicAdd(&cursor[d], 1);
        ssrc[idx] = src[t];
    }
}

// ---------------- all 3 layers' weight transpose+cast in one launch ----------------
__global__ __launch_bounds__(256) void k_wt_all(const float* __restrict__ Wc0, const float* __restrict__ Wl0,
                                                const float* __restrict__ Wc1, const float* __restrict__ Wl1,
                                                const float* __restrict__ Wc2, const float* __restrict__ Wl2,
                                                bf16* __restrict__ Wt0, bf16* __restrict__ Wt1,
                                                bf16* __restrict__ Wt2) {
    int t = blockIdx.x * 256 + threadIdx.x;
    const float* Wc; const float* Wl; bf16* Wt; int HC;
    if (t < 32768)       { Wc = Wc0; Wl = Wl0; Wt = Wt0; HC = 128; }
    else if (t < 65536)  { t -= 32768; Wc = Wc1; Wl = Wl1; Wt = Wt1; HC = 128; }
    else if (t < 106496) { t -= 65536; Wc = Wc2; Wl = Wl2; Wt = Wt2; HC = 160; }
    else return;
    int k = t & 127, c = t >> 7;
    float v = (c < HC) ? Wc[k * HC + c] : Wl[k * HC + c - HC];
    Wt[(size_t)c * 128 + k] = __float2bfloat16(v);
}

// ---------------- MFMA GEMM, col-fused: A read once (or twice for HC=160) ----------------
// block: 64 rows x CT*16 cols; grid (rows/64, 2*HC/(CT*16)).
template <int HC, int CT>
__global__ __launch_bounds__(256) void k_gemm_mfma(const bf16* __restrict__ A, const bf16* __restrict__ Wt,
                                                   bf16* __restrict__ Zh, float* __restrict__ Lin, int n) {
    int tid = threadIdx.x;
    int wv = tid >> 6, lane = tid & 63;
    int quad = lane >> 4, m16 = lane & 15;
    int row0 = blockIdx.x * 64 + wv * 16;
    int col0 = blockIdx.y * (CT * 16);
    f32x4 acc[CT] = {};
    int ar = row0 + m16;
    if (ar >= n) ar = n - 1;
    const short8* Arow = (const short8*)(A + (size_t)ar * 128);
    #pragma unroll
    for (int k8 = 0; k8 < 16; k8 += 4) {
        short8 a = Arow[k8 + quad];
        #pragma unroll
        for (int c = 0; c < CT; c++) {
            const short8* Brow = (const short8*)(Wt + (size_t)(col0 + c * 16 + m16) * 128);
            short8 b = Brow[k8 + quad];
            acc[c] = __builtin_amdgcn_mfma_f32_16x16x32_bf16(a, b, acc[c], 0, 0, 0);
        }
    }
    #pragma unroll
    for (int c = 0; c < CT; c++) {
        int gc = col0 + c * 16 + m16;
        #pragma unroll
        for (int reg = 0; reg < 4; reg++) {
            int r = row0 + quad * 4 + reg;
            if (r >= n) continue;
            float v = acc[c][reg];
            if (gc < HC) Zh[(size_t)r * HC + gc] = __float2bfloat16(v);
            else         Lin[(size_t)r * HC + gc - HC] = v;
        }
    }
}

// ---------------- quantize Zh bf16 -> fp8 e4m3 (8 elems/thread) ----------------
__global__ __launch_bounds__(256) void k_quant(const bf16* __restrict__ Zh, unsigned char* __restrict__ Zq,
                                               int n8) {
    int t = blockIdx.x * 256 + threadIdx.x;
    if (t >= n8) return;
    uint4 v = ((const uint4*)Zh)[t];   // 8 bf16
    float f[8];
    f[0] = bits2f((unsigned short)(v.x & 0xffff)); f[1] = bits2f((unsigned short)(v.x >> 16));
    f[2] = bits2f((unsigned short)(v.y & 0xffff)); f[3] = bits2f((unsigned short)(v.y >> 16));
    f[4] = bits2f((unsigned short)(v.z & 0xffff)); f[5] = bits2f((unsigned short)(v.z >> 16));
    f[6] = bits2f((unsigned short)(v.w & 0xffff)); f[7] = bits2f((unsigned short)(v.w >> 16));
    int lo = 0, hi = 0;
    lo = __builtin_amdgcn_cvt_pk_fp8_f32(f[0], f[1], lo, false);
    lo = __builtin_amdgcn_cvt_pk_fp8_f32(f[2], f[3], lo, true);
    hi = __builtin_amdgcn_cvt_pk_fp8_f32(f[4], f[5], hi, false);
    hi = __builtin_amdgcn_cvt_pk_fp8_f32(f[6], f[7], hi, true);
    ((uint2*)Zq)[t] = make_uint2((unsigned)lo, (unsigned)hi);
}

// ---------------- el/er from bf16 Z ----------------
template <int HC, int D>
__global__ __launch_bounds__(256) void k_elr(const bf16* __restrict__ Z, const float* __restrict__ al,
                                             const float* __restrict__ ar, float* __restrict__ el,
                                             float* __restrict__ er, int n) {
    int t = blockIdx.x * 256 + threadIdx.x;
    if (t >= n * 4) return;
    int node = t >> 2, h = t & 3;
    const __hip_bfloat162* zp = (const __hip_bfloat162*)(Z + (size_t)node * HC + h * D);
    const float* alp = al + h * D;
    const float* arp = ar + h * D;
    float sl = 0.f, sr = 0.f;
    #pragma unroll
    for (int d2 = 0; d2 < D / 2; d2++) {
        __hip_bfloat162 z = zp[d2];
        float zx = b2f(z.x), zy = b2f(z.y);
        sl += zx * alp[2 * d2] + zy * alp[2 * d2 + 1];
        sr += zx * arp[2 * d2] + zy * arp[2 * d2 + 1];
    }
    el[t] = sl;
    er[t] = sr;
}

// ---------------- fused edge softmax + gather (round-12 structure; FP8 Z option) ----------------
template <int HC, int D, bool LAST, bool FP8>
__global__ __launch_bounds__(256) void k_gather(const int* __restrict__ row_ptr, const int* __restrict__ ssrc,
                                                const float* __restrict__ el, const float* __restrict__ er,
                                                const float* __restrict__ bc, const void* __restrict__ Z,
                                                float* __restrict__ Y, const float* __restrict__ bias,
                                                float* __restrict__ out, int n) {
    constexpr int DPL = HC / 16;           // 8 (HC=128) or 10 (HC=160)
    int node = (int)((blockIdx.x * blockDim.x + threadIdx.x) >> 6);
    int lane = threadIdx.x & 63;
    if (node >= n) return;
    int qi = lane >> 4;
    int t16 = lane & 15;
    int hq = t16 >> 2;
    int beg = row_ptr[node], end = row_ptr[node + 1];
    float4 er4 = ((const float4*)er)[node];
    const float4* el4p = (const float4*)el;
    float acc[DPL];
    #pragma unroll
    for (int k = 0; k < DPL; k++) acc[k] = 0.f;
    float ss = 0.f;
    for (int base = beg; base < end; base += 64) {
        int idx = base + lane;
        bool valid = idx < end;
        int s_my = valid ? ssrc[idx] : 0;          // coalesced
        float4 e4 = el4p[s_my];                    // one random 16B per lane
        float x0 = e4.x + er4.x; x0 = x0 > 0.f ? x0 : 0.2f * x0;
        float x1 = e4.y + er4.y; x1 = x1 > 0.f ? x1 : 0.2f * x1;
        float x2 = e4.z + er4.z; x2 = x2 > 0.f ? x2 : 0.2f * x2;
        float x3 = e4.w + er4.w; x3 = x3 > 0.f ? x3 : 0.2f * x3;
        float w0 = valid ? __expf(x0) : 0.f;
        float w1 = valid ? __expf(x1) : 0.f;
        float w2 = valid ? __expf(x2) : 0.f;
        float w3 = valid ? __expf(x3) : 0.f;
        int cnt = end - base; if (cnt > 64) cnt = 64;
        int iters = (cnt + 3) >> 2;                // wave-uniform trip count
        for (int j = 0; j < iters; j++) {
            int sl = qi + (j << 2);                // may exceed cnt-1: w's are 0 there
            int s = __shfl(s_my, sl, 64);
            float a0 = __shfl(w0, sl, 64);
            float a1 = __shfl(w1, sl, 64);
            float a2 = __shfl(w2, sl, 64);
            float a3 = __shfl(w3, sl, 64);
            float wv = (hq & 2) ? ((hq & 1) ? a3 : a2) : ((hq & 1) ? a1 : a0);
            ss += wv;
            if constexpr (FP8) {                   // DPL==8 only
                const unsigned char* zr = (const unsigned char*)Z + (size_t)s * HC + t16 * 8;
                uint2 v = *(const uint2*)zr;       // 8 fp8
                f32x2 p0 = __builtin_amdgcn_cvt_pk_f32_fp8((int)v.x, false);
                f32x2 p1 = __builtin_amdgcn_cvt_pk_f32_fp8((int)v.x, true);
                f32x2 p2 = __builtin_amdgcn_cvt_pk_f32_fp8((int)v.y, false);
                f32x2 p3 = __builtin_amdgcn_cvt_pk_f32_fp8((int)v.y, true);
                acc[0] += wv * p0[0]; acc[1] += wv * p0[1];
                acc[2] += wv * p1[0]; acc[3] += wv * p1[1];
                acc[4] += wv * p2[0]; acc[5] += wv * p2[1];
                acc[6] += wv * p3[0]; acc[7] += wv * p3[1];
            } else if constexpr (DPL == 8) {
                const bf16* zr = (const bf16*)Z + (size_t)s * HC + t16 * 8;
                short8 z8 = *(const short8*)zr;    // 16B aligned
                #pragma unroll
                for (int k = 0; k < 8; k++)
                    acc[k] += wv * bits2f((unsigned short)z8[k]);
            } else {
                const __hip_bfloat162* z2 = (const __hip_bfloat162*)((const bf16*)Z + (size_t)s * HC + t16 * DPL);
                #pragma unroll
                for (int k2 = 0; k2 < DPL / 2; k2++) {
                    __hip_bfloat162 z = z2[k2];
                    acc[2 * k2]     += wv * b2f(z.x);
                    acc[2 * k2 + 1] += wv * b2f(z.y);
                }
            }
        }
    }
    #pragma unroll
    for (int k = 0; k < DPL; k++) {
        acc[k] += __shfl_xor(acc[k], 16, 64);
        acc[k] += __shfl_xor(acc[k], 32, 64);
    }
    ss += __shfl_xor(ss, 16, 64);
    ss += __shfl_xor(ss, 32, 64);
    float inv = (end > beg) ? 1.f / ss : 0.f;
    if constexpr (!LAST) {
        if ((lane & 48) == 0) {
            float* yr = Y + (size_t)node * HC + t16 * DPL;
            const float* bcr = bc + t16 * DPL;
            #pragma unroll
            for (int k = 0; k < DPL; k++) yr[k] += acc[k] * inv + bcr[k];
        }
    } else {
        float yv[DPL];
        const float* lr = Y + (size_t)node * HC + t16 * DPL;   // Y = lin (read-only)
        const float* bcr = bc + t16 * DPL;
        #pragma unroll
        for (int k = 0; k < DPL; k++) yv[k] = acc[k] * inv + bcr[k] + lr[k];
        #pragma unroll
        for (int k = 0; k < DPL; k++) {
            yv[k] += __shfl_xor(yv[k], 4, 64);
            yv[k] += __shfl_xor(yv[k], 8, 64);
        }
        if (lane < 4) {
            float* orow = out + (size_t)node * 40 + t16 * DPL;
            const float* br = bias + t16 * DPL;
            #pragma unroll
            for (int k = 0; k < DPL; k++) orow[k] = 0.25f * yv[k] + br[k];
        }
    }
}

// ---------------- BatchNorm stats: float4 loads + LDS reduce + few atomics ----------------
__global__ __launch_bounds__(256) void k_bn_stats(const float* __restrict__ Y, float* __restrict__ sum,
                                                  float* __restrict__ sumsq, int n) {
    __shared__ float4 lds_s[8][32];
    __shared__ float4 lds_q[8][32];
    int t = threadIdx.x;
    int q = t & 31, g = t >> 5;
    const float4* Y4 = (const float4*)Y;
    float4 s = {0.f, 0.f, 0.f, 0.f}, ss = {0.f, 0.f, 0.f, 0.f};
    for (int r = blockIdx.x * 8 + g; r < n; r += gridDim.x * 8) {
        float4 v = Y4[(size_t)r * 32 + q];
        s.x += v.x; s.y += v.y; s.z += v.z; s.w += v.w;
        ss.x += v.x * v.x; ss.y += v.y * v.y; ss.z += v.z * v.z; ss.w += v.w * v.w;
    }
    lds_s[g][q] = s; lds_q[g][q] = ss;
    __syncthreads();
    if (t < 32) {
        float4 S = lds_s[0][t], Q = lds_q[0][t];
        #pragma unroll
        for (int g2 = 1; g2 < 8; g2++) {
            float4 a = lds_s[g2][t], b = lds_q[g2][t];
            S.x += a.x; S.y += a.y; S.z += a.z; S.w += a.w;
            Q.x += b.x; Q.y += b.y; Q.z += b.z; Q.w += b.w;
        }
        atomicAdd(&sum[4 * t + 0], S.x); atomicAdd(&sum[4 * t + 1], S.y);
        atomicAdd(&sum[4 * t + 2], S.z); atomicAdd(&sum[4 * t + 3], S.w);
        atomicAdd(&sumsq[4 * t + 0], Q.x); atomicAdd(&sumsq[4 * t + 1], Q.y);
        atomicAdd(&sumsq[4 * t + 2], Q.z); atomicAdd(&sumsq[4 * t + 3], Q.w);
    }
}

// BN + ReLU -> bf16, 4 channels/thread
__global__ __launch_bounds__(256) void k_bn_apply(const float* __restrict__ Y, const float* __restrict__ sum,
                                                  const float* __restrict__ sumsq, const float* __restrict__ g,
                                                  const float* __restrict__ b, bf16* __restrict__ out, int n) {
    int t = blockIdx.x * 256 + threadIdx.x;
    if (t >= n * 32) return;
    int c4 = (t & 31) * 4;
    float4 v = ((const float4*)Y)[t];
    float invn = 1.f / (float)n;
    union { bf16 h[4]; short4 s; } u;
    float vv[4] = {v.x, v.y, v.z, v.w};
    #pragma unroll
    for (int k = 0; k < 4; k++) {
        int c = c4 + k;
        float mu = sum[c] * invn;
        float var = sumsq[c] * invn - mu * mu;
        float r = (vv[k] - mu) * rsqrtf(var + 1e-5f) * g[c] + b[c];
        u.h[k] = __float2bfloat16(r > 0.f ? r : 0.f);
    }
    ((short4*)out)[t] = u.s;
}

// ---------------- launch ----------------

extern "C" void kernel_launch(void* const* d_in, const int* in_sizes, int n_in,
                              void* d_out, int out_size, void* d_ws, size_t ws_size,
                              hipStream_t stream) {
    (void)n_in; (void)out_size; (void)ws_size;
    const int N = in_sizes[0] / 128;
    const int E = in_sizes[1];

    const int* src = (const int*)d_in[1];
    const int* dst = (const int*)d_in[2];
    float* out = (float*)d_out;

    char* p = (char*)d_ws;
    auto carve = [&](size_t bytes) {
        void* q = (void*)p;
        p += (bytes + 255) & ~(size_t)255;
        return q;
    };
    int*   mode    = (int*)  carve(256);
    bf16*  h_bf    = (bf16*) carve((size_t)N * 128 * 2);
    bf16*  zh      = (bf16*) carve((size_t)N * 160 * 2);
    unsigned char* zq = (unsigned char*)carve((size_t)N * 128);
    float* lin     = (float*)carve((size_t)N * 160 * 4);
    float* el      = (float*)carve((size_t)N * 4 * 4);
    float* er      = (float*)carve((size_t)N * 4 * 4);
    float* bn0     = (float*)carve(256 * 4);
    float* bn1     = (float*)carve(256 * 4);
    int*   counts  = (int*)  carve((size_t)N * 4);
    int*   row_ptr = (int*)  carve((size_t)(N + 1) * 4);
    int*   cursor  = (int*)  carve((size_t)N * 4);
    int*   ssrc    = (int*)  carve((size_t)E * 4);
    bf16*  Wt0     = (bf16*) carve((size_t)2 * 128 * 128 * 2);
    bf16*  Wt1     = (bf16*) carve((size_t)2 * 128 * 128 * 2);
    bf16*  Wt2     = (bf16*) carve((size_t)2 * 160 * 128 * 2);
    float* W32[23];
    for (int i = 3; i < 23; i++) W32[i] = (float*)carve((size_t)in_sizes[i] * 4);

    // staging
    k_probe<<<1, 64, 0, stream>>>(d_in[0], mode);
    k_stage_bf<<<(N * 32 + 255) / 256, 256, 0, stream>>>(d_in[0], h_bf, N * 32, mode);
    StageArgs sa;
    for (int i = 3; i < 23; i++) sa.d[i - 3] = StageDesc{d_in[i], W32[i], in_sizes[i]};
    k_stage_all<<<dim3(20, 8), 256, 0, stream>>>(sa, mode);

    const float* Wc[3] = {W32[3],  W32[8],  W32[13]};
    const float* al[3] = {W32[4],  W32[9],  W32[14]};
    const float* ar[3] = {W32[5],  W32[10], W32[15]};
    const float* bc[3] = {W32[6],  W32[11], W32[16]};
    const float* Wl[3] = {W32[7],  W32[12], W32[17]};
    const float* g0 = W32[18];
    const float* b0 = W32[19];
    const float* g1 = W32[20];
    const float* b1 = W32[21];
    const float* bias_last = W32[22];

    k_wt_all<<<(106496 + 255) / 256, 256, 0, stream>>>(Wc[0], Wl[0], Wc[1], Wl[1], Wc[2], Wl[2],
                                                       Wt0, Wt1, Wt2);
    bf16* Wt[3] = {Wt0, Wt1, Wt2};

    const int EB = (E + 255) / 256;
    const int GB_ROWS = (N + 63) / 64;
    const int NODE_BLK = (N + 3) / 4;

    // CSR by dst (shared across layers) + bn buffer zeroing
    k_zero_all<<<(N + 255) / 256, 256, 0, stream>>>(counts, bn0, bn1, N);
    k_hist<<<EB, 256, 0, stream>>>(dst, counts, E);
    k_scan<<<1, 1024, 0, stream>>>(counts, row_ptr, cursor, N);
    k_scatter<<<EB, 256, 0, stream>>>(src, dst, cursor, ssrc, E);

    // ---- layers 0 and 1 (HC=128, D=32): col-fused GEMM (CT=16, y=1), fp8 gather ----
    for (int l = 0; l < 2; l++) {
        float* bnb = (l == 0) ? bn0 : bn1;
        k_gemm_mfma<128, 16><<<dim3(GB_ROWS, 1), 256, 0, stream>>>(h_bf, Wt[l], zh, lin, N);
        k_quant<<<(N * 16 + 255) / 256, 256, 0, stream>>>(zh, zq, N * 16);
        k_elr<128, 32><<<(N * 4 + 255) / 256, 256, 0, stream>>>(zh, al[l], ar[l], el, er, N);
        k_gather<128, 32, false, true><<<NODE_BLK, 256, 0, stream>>>(row_ptr, ssrc, el, er, bc[l], zq,
                                                                     lin, nullptr, nullptr, N);
        k_bn_stats<<<512, 256, 0, stream>>>(lin, bnb, bnb + 128, N);
        const float* gg = (l == 0) ? g0 : g1;
        const float* bb = (l == 0) ? b0 : b1;
        k_bn_apply<<<(N * 32 + 255) / 256, 256, 0, stream>>>(lin, bnb, bnb + 128, gg, bb, h_bf, N);
    }

    // ---- layer 2 (HC=160, D=40): CT=10, y=2; bf16 gather with fused out ----
    k_gemm_mfma<160, 10><<<dim3(GB_ROWS, 2), 256, 0, stream>>>(h_bf, Wt[2], zh, lin, N);
    k_elr<160, 40><<<(N * 4 + 255) / 256, 256, 0, stream>>>(zh, al[2], ar[2], el, er, N);
    k_gather<160, 40, true, false><<<NODE_BLK, 256, 0, stream>>>(row_ptr, ssrc, el, er, bc[2], zh,
                                                                 lin, bias_last, out, N);
}

// Round 15
// 613.694 us; speedup vs baseline: 4.6525x; 1.0999x over previous
//
#include <hip/hip_runtime.h>
#include <hip/hip_bf16.h>

typedef __hip_bfloat16 bf16;
typedef __attribute__((ext_vector_type(8))) short short8;   // 8 bf16 = 4 VGPRs
typedef __attribute__((ext_vector_type(4))) float f32x4;

__device__ __forceinline__ float b2f(bf16 x) { return __bfloat162float(x); }
__device__ __forceinline__ float bits2f(unsigned short u) {
    return __uint_as_float(((unsigned)u) << 16);
}

// ---------------- dtype probe (inputs proven fp32; kept as cheap insurance) ----------------
__global__ __launch_bounds__(64) void k_probe(const void* __restrict__ feat, int* __restrict__ mode) {
    const bf16* p = (const bf16*)feat;
    int lane = threadIdx.x;
    float m = 0.f;
    for (int i = lane; i < 2048; i += 64) {
        float v = fabsf(b2f(p[2 * i]));
        if (!(v < 1e30f)) v = 1e30f;
        m = fmaxf(m, v);
    }
    #pragma unroll
    for (int off = 32; off > 0; off >>= 1) m = fmaxf(m, __shfl_xor(m, off, 64));
    if (lane == 0) *mode = (m > 1e8f) ? 1 : 0;   // 1 = inputs are fp32
}

// stage feat -> bf16, 4 elements/thread (float4 in, short4 out)
__global__ __launch_bounds__(256) void k_stage_bf(const void* __restrict__ in, bf16* __restrict__ out,
                                                  int n4, const int* __restrict__ mode) {
    int t = blockIdx.x * 256 + threadIdx.x;
    if (t >= n4) return;
    if (*mode) {
        float4 v = ((const float4*)in)[t];
        union { bf16 h[4]; short4 s; } u;
        u.h[0] = __float2bfloat16(v.x);
        u.h[1] = __float2bfloat16(v.y);
        u.h[2] = __float2bfloat16(v.z);
        u.h[3] = __float2bfloat16(v.w);
        ((short4*)out)[t] = u.s;
    } else {
        ((short4*)out)[t] = ((const short4*)in)[t];
    }
}

// all 20 weight tensors; grid (20, 8): x = tensor, y = chunk
struct StageDesc { const void* src; float* dst; int n; };
struct StageArgs { StageDesc d[20]; };
__global__ __launch_bounds__(256) void k_stage_all(StageArgs args, const int* __restrict__ mode) {
    const StageDesc sd = args.d[blockIdx.x];
    int m = *mode;
    for (int t = blockIdx.y * 256 + threadIdx.x; t < sd.n; t += 8 * 256) {
        float v = m ? ((const float*)sd.src)[t] : b2f(((const bf16*)sd.src)[t]);
        sd.dst[t] = v;
    }
}

// zero counts[N] and bn partial buffers (both layers)
__global__ __launch_bounds__(256) void k_zero_all(int* __restrict__ counts, float* __restrict__ bn0,
                                                  float* __restrict__ bn1, int n) {
    int t = blockIdx.x * 256 + threadIdx.x;
    if (t < n) counts[t] = 0;
    if (t < 256) { bn0[t] = 0.f; bn1[t] = 0.f; }
}

// ---------------- CSR build (by dst) ----------------

__global__ __launch_bounds__(256) void k_hist(const int* __restrict__ dst, int* __restrict__ counts, int e) {
    int t = blockIdx.x * 256 + threadIdx.x;
    if (t < e) atomicAdd(&counts[dst[t]], 1);
}

// round-10 proven block-strided scan
__global__ __launch_bounds__(1024) void k_scan(const int* __restrict__ counts, int* __restrict__ row_ptr,
                                               int* __restrict__ cursor, int n) {
    __shared__ int wsum[16];
    __shared__ int carry_s;
    int lane = threadIdx.x & 63, w = threadIdx.x >> 6;
    if (threadIdx.x == 0) carry_s = 0;
    __syncthreads();
    for (int base = 0; base < n; base += 1024) {
        int i = base + (int)threadIdx.x;
        int v = (i < n) ? counts[i] : 0;
        int x = v;
        #pragma unroll
        for (int off = 1; off < 64; off <<= 1) {
            int t = __shfl_up(x, off, 64);
            if (lane >= off) x += t;
        }
        if (lane == 63) wsum[w] = x;
        __syncthreads();
        if (w == 0 && lane < 16) {
            int s = wsum[lane];
            #pragma unroll
            for (int off = 1; off < 16; off <<= 1) {
                int t = __shfl_up(s, off, 64);
                if (lane >= off) s += t;
            }
            wsum[lane] = s;
        }
        __syncthreads();
        int carry = carry_s;
        int woff = (w == 0) ? 0 : wsum[w - 1];
        int excl = carry + woff + x - v;
        if (i < n) { row_ptr[i] = excl; cursor[i] = excl; }
        __syncthreads();
        if (threadIdx.x == 0) carry_s = carry + wsum[15];
        __syncthreads();
    }
    if (threadIdx.x == 0) row_ptr[n] = carry_s;
}

__global__ __launch_bounds__(256) void k_scatter(const int* __restrict__ src, const int* __restrict__ dst,
                                                 int* __restrict__ cursor, int* __restrict__ ssrc, int e) {
    int t = blockIdx.x * 256 + threadIdx.x;
    if (t < e) {
        int d = dst[t];
        int idx = atomicAdd(&cursor[d], 1);
        ssrc[idx] = src[t];
    }
}

// ---------------- all 3 layers' weight transpose+cast in one launch ----------------
__global__ __launch_bounds__(256) void k_wt_all(const float* __restrict__ Wc0, const float* __restrict__ Wl0,
                                                const float* __restrict__ Wc1, const float* __restrict__ Wl1,
                                                const float* __restrict__ Wc2, const float* __restrict__ Wl2,
                                                bf16* __restrict__ Wt0, bf16* __restrict__ Wt1,
                                                bf16* __restrict__ Wt2) {
    int t = blockIdx.x * 256 + threadIdx.x;
    const float* Wc; const float* Wl; bf16* Wt; int HC;
    if (t < 32768)       { Wc = Wc0; Wl = Wl0; Wt = Wt0; HC = 128; }
    else if (t < 65536)  { t -= 32768; Wc = Wc1; Wl = Wl1; Wt = Wt1; HC = 128; }
    else if (t < 106496) { t -= 65536; Wc = Wc2; Wl = Wl2; Wt = Wt2; HC = 160; }
    else return;
    int k = t & 127, c = t >> 7;
    float v = (c < HC) ? Wc[k * HC + c] : Wl[k * HC + c - HC];
    Wt[(size_t)c * 128 + k] = __float2bfloat16(v);
}

// ---------------- MFMA GEMM, col-fused: A read once (or twice for HC=160) ----------------
template <int HC, int CT>
__global__ __launch_bounds__(256) void k_gemm_mfma(const bf16* __restrict__ A, const bf16* __restrict__ Wt,
                                                   bf16* __restrict__ Zh, float* __restrict__ Lin, int n) {
    int tid = threadIdx.x;
    int wv = tid >> 6, lane = tid & 63;
    int quad = lane >> 4, m16 = lane & 15;
    int row0 = blockIdx.x * 64 + wv * 16;
    int col0 = blockIdx.y * (CT * 16);
    f32x4 acc[CT] = {};
    int ar = row0 + m16;
    if (ar >= n) ar = n - 1;
    const short8* Arow = (const short8*)(A + (size_t)ar * 128);
    #pragma unroll
    for (int k8 = 0; k8 < 16; k8 += 4) {
        short8 a = Arow[k8 + quad];
        #pragma unroll
        for (int c = 0; c < CT; c++) {
            const short8* Brow = (const short8*)(Wt + (size_t)(col0 + c * 16 + m16) * 128);
            short8 b = Brow[k8 + quad];
            acc[c] = __builtin_amdgcn_mfma_f32_16x16x32_bf16(a, b, acc[c], 0, 0, 0);
        }
    }
    #pragma unroll
    for (int c = 0; c < CT; c++) {
        int gc = col0 + c * 16 + m16;
        #pragma unroll
        for (int reg = 0; reg < 4; reg++) {
            int r = row0 + quad * 4 + reg;
            if (r >= n) continue;
            float v = acc[c][reg];
            if (gc < HC) Zh[(size_t)r * HC + gc] = __float2bfloat16(v);
            else         Lin[(size_t)r * HC + gc - HC] = v;
        }
    }
}

// ---------------- el/er from bf16 Z ----------------
template <int HC, int D>
__global__ __launch_bounds__(256) void k_elr(const bf16* __restrict__ Z, const float* __restrict__ al,
                                             const float* __restrict__ ar, float* __restrict__ el,
                                             float* __restrict__ er, int n) {
    int t = blockIdx.x * 256 + threadIdx.x;
    if (t >= n * 4) return;
    int node = t >> 2, h = t & 3;
    const __hip_bfloat162* zp = (const __hip_bfloat162*)(Z + (size_t)node * HC + h * D);
    const float* alp = al + h * D;
    const float* arp = ar + h * D;
    float sl = 0.f, sr = 0.f;
    #pragma unroll
    for (int d2 = 0; d2 < D / 2; d2++) {
        __hip_bfloat162 z = zp[d2];
        float zx = b2f(z.x), zy = b2f(z.y);
        sl += zx * alp[2 * d2] + zy * alp[2 * d2 + 1];
        sr += zx * arp[2 * d2] + zy * arp[2 * d2 + 1];
    }
    el[t] = sl;
    er[t] = sr;
}

// ---------------- fused edge softmax + gather (round-12 proven, bf16 Z) ----------------
template <int HC, int D, bool LAST>
__global__ __launch_bounds__(256) void k_gather(const int* __restrict__ row_ptr, const int* __restrict__ ssrc,
                                                const float* __restrict__ el, const float* __restrict__ er,
                                                const float* __restrict__ bc, const bf16* __restrict__ Z,
                                                float* __restrict__ Y, const float* __restrict__ bias,
                                                float* __restrict__ out, int n) {
    constexpr int DPL = HC / 16;           // 8 (HC=128) or 10 (HC=160)
    int node = (int)((blockIdx.x * blockDim.x + threadIdx.x) >> 6);
    int lane = threadIdx.x & 63;
    if (node >= n) return;
    int qi = lane >> 4;
    int t16 = lane & 15;
    int hq = t16 >> 2;
    int beg = row_ptr[node], end = row_ptr[node + 1];
    float4 er4 = ((const float4*)er)[node];
    const float4* el4p = (const float4*)el;
    const bf16* Zt = Z + t16 * DPL;
    float acc[DPL];
    #pragma unroll
    for (int k = 0; k < DPL; k++) acc[k] = 0.f;
    float ss = 0.f;
    for (int base = beg; base < end; base += 64) {
        int idx = base + lane;
        bool valid = idx < end;
        int s_my = valid ? ssrc[idx] : 0;          // coalesced
        float4 e4 = el4p[s_my];                    // one random 16B per lane
        float x0 = e4.x + er4.x; x0 = x0 > 0.f ? x0 : 0.2f * x0;
        float x1 = e4.y + er4.y; x1 = x1 > 0.f ? x1 : 0.2f * x1;
        float x2 = e4.z + er4.z; x2 = x2 > 0.f ? x2 : 0.2f * x2;
        float x3 = e4.w + er4.w; x3 = x3 > 0.f ? x3 : 0.2f * x3;
        float w0 = valid ? __expf(x0) : 0.f;
        float w1 = valid ? __expf(x1) : 0.f;
        float w2 = valid ? __expf(x2) : 0.f;
        float w3 = valid ? __expf(x3) : 0.f;
        int cnt = end - base; if (cnt > 64) cnt = 64;
        int iters = (cnt + 3) >> 2;                // wave-uniform trip count
        for (int j = 0; j < iters; j++) {
            int sl = qi + (j << 2);                // may exceed cnt-1: w's are 0 there
            int s = __shfl(s_my, sl, 64);
            float a0 = __shfl(w0, sl, 64);
            float a1 = __shfl(w1, sl, 64);
            float a2 = __shfl(w2, sl, 64);
            float a3 = __shfl(w3, sl, 64);
            float wv = (hq & 2) ? ((hq & 1) ? a3 : a2) : ((hq & 1) ? a1 : a0);
            ss += wv;
            const bf16* zr = Zt + (size_t)s * HC;
            if constexpr (DPL == 8) {
                short8 z8 = *(const short8*)zr;    // 16B aligned
                #pragma unroll
                for (int k = 0; k < 8; k++)
                    acc[k] += wv * bits2f((unsigned short)z8[k]);
            } else {
                const __hip_bfloat162* z2 = (const __hip_bfloat162*)zr;
                #pragma unroll
                for (int k2 = 0; k2 < DPL / 2; k2++) {
                    __hip_bfloat162 z = z2[k2];
                    acc[2 * k2]     += wv * b2f(z.x);
                    acc[2 * k2 + 1] += wv * b2f(z.y);
                }
            }
        }
    }
    #pragma unroll
    for (int k = 0; k < DPL; k++) {
        acc[k] += __shfl_xor(acc[k], 16, 64);
        acc[k] += __shfl_xor(acc[k], 32, 64);
    }
    ss += __shfl_xor(ss, 16, 64);
    ss += __shfl_xor(ss, 32, 64);
    float inv = (end > beg) ? 1.f / ss : 0.f;
    if constexpr (!LAST) {
        if ((lane & 48) == 0) {
            float* yr = Y + (size_t)node * HC + t16 * DPL;
            const float* bcr = bc + t16 * DPL;
            #pragma unroll
            for (int k = 0; k < DPL; k++) yr[k] += acc[k] * inv + bcr[k];
        }
    } else {
        float yv[DPL];
        const float* lr = Y + (size_t)node * HC + t16 * DPL;   // Y = lin (read-only)
        const float* bcr = bc + t16 * DPL;
        #pragma unroll
        for (int k = 0; k < DPL; k++) yv[k] = acc[k] * inv + bcr[k] + lr[k];
        #pragma unroll
        for (int k = 0; k < DPL; k++) {
            yv[k] += __shfl_xor(yv[k], 4, 64);
            yv[k] += __shfl_xor(yv[k], 8, 64);
        }
        if (lane < 4) {
            float* orow = out + (size_t)node * 40 + t16 * DPL;
            const float* br = bias + t16 * DPL;
            #pragma unroll
            for (int k = 0; k < DPL; k++) orow[k] = 0.25f * yv[k] + br[k];
        }
    }
}

// ---------------- BatchNorm stats: 128 blocks (low atomic contention) + pipelined loads ----------------
// thread t: channel quad q=(t&31), row group g=(t>>5) of 8. 128 blocks => 32k atomics,
// 128 per address (r13/14's 512 blocks = 512/addr serial chains pinned the kernel at ~56us).
__global__ __launch_bounds__(256) void k_bn_stats(const float* __restrict__ Y, float* __restrict__ sum,
                                                  float* __restrict__ sumsq, int n) {
    __shared__ float4 lds_s[8][32];
    __shared__ float4 lds_q[8][32];
    int t = threadIdx.x;
    int q = t & 31, g = t >> 5;
    const float4* Y4 = (const float4*)Y;
    float4 s = {0.f, 0.f, 0.f, 0.f}, ss = {0.f, 0.f, 0.f, 0.f};
    const int stride = 128 * 8;
    int r = blockIdx.x * 8 + g;
    // 2x software pipeline: two independent loads in flight
    for (; r + stride < n; r += 2 * stride) {
        float4 v0 = Y4[(size_t)r * 32 + q];
        float4 v1 = Y4[(size_t)(r + stride) * 32 + q];
        s.x += v0.x; s.y += v0.y; s.z += v0.z; s.w += v0.w;
        ss.x += v0.x * v0.x; ss.y += v0.y * v0.y; ss.z += v0.z * v0.z; ss.w += v0.w * v0.w;
        s.x += v1.x; s.y += v1.y; s.z += v1.z; s.w += v1.w;
        ss.x += v1.x * v1.x; ss.y += v1.y * v1.y; ss.z += v1.z * v1.z; ss.w += v1.w * v1.w;
    }
    if (r < n) {
        float4 v = Y4[(size_t)r * 32 + q];
        s.x += v.x; s.y += v.y; s.z += v.z; s.w += v.w;
        ss.x += v.x * v.x; ss.y += v.y * v.y; ss.z += v.z * v.z; ss.w += v.w * v.w;
    }
    lds_s[g][q] = s; lds_q[g][q] = ss;
    __syncthreads();
    if (t < 32) {
        float4 S = lds_s[0][t], Q = lds_q[0][t];
        #pragma unroll
        for (int g2 = 1; g2 < 8; g2++) {
            float4 a = lds_s[g2][t], b = lds_q[g2][t];
            S.x += a.x; S.y += a.y; S.z += a.z; S.w += a.w;
            Q.x += b.x; Q.y += b.y; Q.z += b.z; Q.w += b.w;
        }
        atomicAdd(&sum[4 * t + 0], S.x); atomicAdd(&sum[4 * t + 1], S.y);
        atomicAdd(&sum[4 * t + 2], S.z); atomicAdd(&sum[4 * t + 3], S.w);
        atomicAdd(&sumsq[4 * t + 0], Q.x); atomicAdd(&sumsq[4 * t + 1], Q.y);
        atomicAdd(&sumsq[4 * t + 2], Q.z); atomicAdd(&sumsq[4 * t + 3], Q.w);
    }
}

// BN + ReLU -> bf16, 4 channels/thread
__global__ __launch_bounds__(256) void k_bn_apply(const float* __restrict__ Y, const float* __restrict__ sum,
                                                  const float* __restrict__ sumsq, const float* __restrict__ g,
                                                  const float* __restrict__ b, bf16* __restrict__ out, int n) {
    int t = blockIdx.x * 256 + threadIdx.x;
    if (t >= n * 32) return;
    int c4 = (t & 31) * 4;
    float4 v = ((const float4*)Y)[t];
    float invn = 1.f / (float)n;
    union { bf16 h[4]; short4 s; } u;
    float vv[4] = {v.x, v.y, v.z, v.w};
    #pragma unroll
    for (int k = 0; k < 4; k++) {
        int c = c4 + k;
        float mu = sum[c] * invn;
        float var = sumsq[c] * invn - mu * mu;
        float r = (vv[k] - mu) * rsqrtf(var + 1e-5f) * g[c] + b[c];
        u.h[k] = __float2bfloat16(r > 0.f ? r : 0.f);
    }
    ((short4*)out)[t] = u.s;
}

// ---------------- launch ----------------

extern "C" void kernel_launch(void* const* d_in, const int* in_sizes, int n_in,
                              void* d_out, int out_size, void* d_ws, size_t ws_size,
                              hipStream_t stream) {
    (void)n_in; (void)out_size; (void)ws_size;
    const int N = in_sizes[0] / 128;
    const int E = in_sizes[1];

    const int* src = (const int*)d_in[1];
    const int* dst = (const int*)d_in[2];
    float* out = (float*)d_out;

    char* p = (char*)d_ws;
    auto carve = [&](size_t bytes) {
        void* q = (void*)p;
        p += (bytes + 255) & ~(size_t)255;
        return q;
    };
    int*   mode    = (int*)  carve(256);
    bf16*  h_bf    = (bf16*) carve((size_t)N * 128 * 2);
    bf16*  zh      = (bf16*) carve((size_t)N * 160 * 2);
    float* lin     = (float*)carve((size_t)N * 160 * 4);
    float* el      = (float*)carve((size_t)N * 4 * 4);
    float* er      = (float*)carve((size_t)N * 4 * 4);
    float* bn0     = (float*)carve(256 * 4);
    float* bn1     = (float*)carve(256 * 4);
    int*   counts  = (int*)  carve((size_t)N * 4);
    int*   row_ptr = (int*)  carve((size_t)(N + 1) * 4);
    int*   cursor  = (int*)  carve((size_t)N * 4);
    int*   ssrc    = (int*)  carve((size_t)E * 4);
    bf16*  Wt0     = (bf16*) carve((size_t)2 * 128 * 128 * 2);
    bf16*  Wt1     = (bf16*) carve((size_t)2 * 128 * 128 * 2);
    bf16*  Wt2     = (bf16*) carve((size_t)2 * 160 * 128 * 2);
    float* W32[23];
    for (int i = 3; i < 23; i++) W32[i] = (float*)carve((size_t)in_sizes[i] * 4);

    // staging
    k_probe<<<1, 64, 0, stream>>>(d_in[0], mode);
    k_stage_bf<<<(N * 32 + 255) / 256, 256, 0, stream>>>(d_in[0], h_bf, N * 32, mode);
    StageArgs sa;
    for (int i = 3; i < 23; i++) sa.d[i - 3] = StageDesc{d_in[i], W32[i], in_sizes[i]};
    k_stage_all<<<dim3(20, 8), 256, 0, stream>>>(sa, mode);

    const float* Wc[3] = {W32[3],  W32[8],  W32[13]};
    const float* al[3] = {W32[4],  W32[9],  W32[14]};
    const float* ar[3] = {W32[5],  W32[10], W32[15]};
    const float* bc[3] = {W32[6],  W32[11], W32[16]};
    const float* Wl[3] = {W32[7],  W32[12], W32[17]};
    const float* g0 = W32[18];
    const float* b0 = W32[19];
    const float* g1 = W32[20];
    const float* b1 = W32[21];
    const float* bias_last = W32[22];

    k_wt_all<<<(106496 + 255) / 256, 256, 0, stream>>>(Wc[0], Wl[0], Wc[1], Wl[1], Wc[2], Wl[2],
                                                       Wt0, Wt1, Wt2);
    bf16* Wt[3] = {Wt0, Wt1, Wt2};

    const int EB = (E + 255) / 256;
    const int GB_ROWS = (N + 63) / 64;
    const int NODE_BLK = (N + 3) / 4;

    // CSR by dst (shared across layers) + bn buffer zeroing
    k_zero_all<<<(N + 255) / 256, 256, 0, stream>>>(counts, bn0, bn1, N);
    k_hist<<<EB, 256, 0, stream>>>(dst, counts, E);
    k_scan<<<1, 1024, 0, stream>>>(counts, row_ptr, cursor, N);
    k_scatter<<<EB, 256, 0, stream>>>(src, dst, cursor, ssrc, E);

    // ---- layers 0 and 1 (HC=128, D=32): col-fused GEMM (CT=16, y=1), bf16 gather ----
    for (int l = 0; l < 2; l++) {
        float* bnb = (l == 0) ? bn0 : bn1;
        k_gemm_mfma<128, 16><<<dim3(GB_ROWS, 1), 256, 0, stream>>>(h_bf, Wt[l], zh, lin, N);
        k_elr<128, 32><<<(N * 4 + 255) / 256, 256, 0, stream>>>(zh, al[l], ar[l], el, er, N);
        k_gather<128, 32, false><<<NODE_BLK, 256, 0, stream>>>(row_ptr, ssrc, el, er, bc[l], zh,
                                                               lin, nullptr, nullptr, N);
        k_bn_stats<<<128, 256, 0, stream>>>(lin, bnb, bnb + 128, N);
        const float* gg = (l == 0) ? g0 : g1;
        const float* bb = (l == 0) ? b0 : b1;
        k_bn_apply<<<(N * 32 + 255) / 256, 256, 0, stream>>>(lin, bnb, bnb + 128, gg, bb, h_bf, N);
    }

    // ---- layer 2 (HC=160, D=40): CT=10, y=2; bf16 gather with fused out ----
    k_gemm_mfma<160, 10><<<dim3(GB_ROWS, 2), 256, 0, stream>>>(h_bf, Wt[2], zh, lin, N);
    k_elr<160, 40><<<(N * 4 + 255) / 256, 256, 0, stream>>>(zh, al[2], ar[2], el, er, N);
    k_gather<160, 40, true><<<NODE_BLK, 256, 0, stream>>>(row_ptr, ssrc, el, er, bc[2], zh,
                                                          lin, bias_last, out, N);
}